// Round 9
// baseline (3038.798 us; speedup 1.0000x reference)
//
#include <hip/hip_runtime.h>
#include <hip/hip_bf16.h>
#include <math.h>

// ---------------- types & helpers ----------------
typedef __attribute__((ext_vector_type(8))) short short8;   // 8 x bf16 (4 VGPRs)
typedef __attribute__((ext_vector_type(4))) float f32x4;

typedef unsigned short u16;

__device__ __forceinline__ u16 f2bf(float f) {
    union { float f; unsigned int u; } v; v.f = f;
    unsigned int u = v.u;
    unsigned int r = (u + 0x7fffu + ((u >> 16) & 1u)) >> 16;  // RNE
    return (u16)r;
}
__device__ __forceinline__ float bf2f(u16 u) {
    union { unsigned int u; float f; } v; v.u = ((unsigned int)u) << 16;
    return v.f;
}

// async global->LDS 16B copy (wave base + lane*16 dest, per-lane global src).
__device__ __forceinline__ void gload16(const void* g, void* l) {
    __builtin_amdgcn_global_load_lds(
        (const __attribute__((address_space(1))) void*)g,
        (__attribute__((address_space(3))) void*)l, 16, 0, 0);
}

// ---------------- weight cast: f32 -> bf16 (pad region zeroed) ----------------
__global__ __launch_bounds__(256) void castw_kernel(const float* __restrict__ src,
                                                    u16* __restrict__ dst,
                                                    long n, long npad) {
    long i = ((long)blockIdx.x * 256 + threadIdx.x) * 4;
    const long stride = (long)gridDim.x * 1024;
    for (; i < npad; i += stride) {
        ushort4 o;
        if (i < n) {
            float4 v = *reinterpret_cast<const float4*>(src + i);
            o.x = f2bf(v.x); o.y = f2bf(v.y); o.z = f2bf(v.z); o.w = f2bf(v.w);
        } else {
            o = make_ushort4(0, 0, 0, 0);
        }
        *reinterpret_cast<ushort4*>(dst + i) = o;
    }
}

// ---------------- embed: x = wte[idx] + wpe[t] ----------------
__global__ __launch_bounds__(256) void embed_kernel(const int* __restrict__ idx,
                                                    const float* __restrict__ wte,
                                                    const float* __restrict__ wpe,
                                                    float* __restrict__ x) {
    const int row = blockIdx.x;            // b*1024 + t
    const int tid = threadIdx.x;
    const int t = row & 1023;
    const int tok = idx[row];
    const float* we = wte + (size_t)tok * 768;
    const float* pe = wpe + (size_t)t * 768;
    float* xr = x + (size_t)row * 768;
    xr[tid]       = we[tid]       + pe[tid];
    xr[tid + 256] = we[tid + 256] + pe[tid + 256];
    xr[tid + 512] = we[tid + 512] + pe[tid + 512];
}

// ---------------- LayerNorm: wave-per-row (no LDS, no barriers) ----------------
__global__ __launch_bounds__(256) void ln_kernel(const float* __restrict__ x,
                                                 const float* __restrict__ w,
                                                 const float* __restrict__ b,
                                                 u16* __restrict__ out) {
    const int wid = threadIdx.x >> 6, lane = threadIdx.x & 63;
    const int row = blockIdx.x * 4 + wid;
    const float* xr = x + (size_t)row * 768;
    const float4 v0 = *reinterpret_cast<const float4*>(xr + lane * 4);
    const float4 v1 = *reinterpret_cast<const float4*>(xr + 256 + lane * 4);
    const float4 v2 = *reinterpret_cast<const float4*>(xr + 512 + lane * 4);
    float s = v0.x + v0.y + v0.z + v0.w + v1.x + v1.y + v1.z + v1.w
            + v2.x + v2.y + v2.z + v2.w;
    float q = v0.x * v0.x + v0.y * v0.y + v0.z * v0.z + v0.w * v0.w
            + v1.x * v1.x + v1.y * v1.y + v1.z * v1.z + v1.w * v1.w
            + v2.x * v2.x + v2.y * v2.y + v2.z * v2.z + v2.w * v2.w;
    #pragma unroll
    for (int off = 32; off >= 1; off >>= 1) {
        s += __shfl_xor(s, off);
        q += __shfl_xor(q, off);
    }
    const float mean = s * (1.f / 768.f);
    const float var = q * (1.f / 768.f) - mean * mean;
    const float rstd = rsqrtf(var + 1e-5f);
    u16* orow = out + (size_t)row * 768;
    #pragma unroll
    for (int seg = 0; seg < 3; seg++) {
        const float4 v = seg == 0 ? v0 : (seg == 1 ? v1 : v2);
        const float4 wv = *reinterpret_cast<const float4*>(w + seg * 256 + lane * 4);
        const float4 bv = *reinterpret_cast<const float4*>(b + seg * 256 + lane * 4);
        ushort4 ov;
        ov.x = f2bf((v.x - mean) * rstd * wv.x + bv.x);
        ov.y = f2bf((v.y - mean) * rstd * wv.y + bv.y);
        ov.z = f2bf((v.z - mean) * rstd * wv.z + bv.z);
        ov.w = f2bf((v.w - mean) * rstd * wv.w + bv.w);
        *reinterpret_cast<ushort4*>(orow + seg * 256 + lane * 4) = ov;
    }
}

// =========== 256x128-tile 2-phase GEMM, 512 threads ==================
// C[m,n] = sum_k A[m,k]*B[n,k].  BM=256, BN=128, BK=32.  8 waves = 4M x 2N.
// 2-phase dbuf, counted vmcnt(3).  ORDER: 0 = m-fastest (B-panel L2 reuse),
// 1 = n-fastest (A-tile L2 reuse; for lm_head where C-write evicts L3).
// nmt = tile count of the FAST dimension.
// EPI: 0 = +bias -> bf16; 2 = +bias+GELU -> bf16; 3 = plain f32 (n<N guard,
//      padded-LDS transpose + float4 stores)
template<int EPI, int ORDER>
__global__ __launch_bounds__(512) void gemm_big(
        const u16* __restrict__ A, int lda,
        const u16* __restrict__ B, int ldb,
        const float* __restrict__ bias,
        void* __restrict__ Cout, int ldc,
        int N, int K, int nmt) {
    __shared__ __align__(16) u16 lds[2][384 * 32];   // [buf]: A = [0,8192) u16, B = [8192,12288)
    const int tid = threadIdx.x;
    const int lane = tid & 63, wid = tid >> 6;
    const int nwg = gridDim.x;
    const int o = blockIdx.x;
    const int wg = (o & 7) * (nwg >> 3) + (o >> 3);   // bijective XCD swizzle (grid%8==0)
    int m0, n0;
    if (ORDER == 0) { m0 = (wg % nmt) * 256; n0 = (wg / nmt) * 128; }
    else            { n0 = (wg % nmt) * 128; m0 = (wg / nmt) * 256; }

    const int wm = (wid >> 1) * 64, wn = (wid & 1) * 64;
    const int l16 = lane & 15;
    const int qid = lane >> 4;
    const int xq8 = ((qid ^ (l16 & 3)) * 8);

    const int ar = tid >> 2, aq = (tid & 3) ^ (ar & 3);
    const size_t a_src0 = (size_t)(m0 + ar) * lda + aq * 8;
    const size_t a_src1 = (size_t)(m0 + ar + 128) * lda + aq * 8;
    const size_t b_src = (size_t)(n0 + ar) * ldb + aq * 8;

    f32x4 acc[4][4];
    #pragma unroll
    for (int i = 0; i < 4; i++)
        #pragma unroll
        for (int j = 0; j < 4; j++)
            acc[i][j] = (f32x4){0.f, 0.f, 0.f, 0.f};

    const int nk = K >> 5;
    gload16(A + a_src0, lds[0] + tid * 8);
    gload16(A + a_src1, lds[0] + tid * 8 + 4096);
    gload16(B + b_src,  lds[0] + tid * 8 + 8192);

    for (int t = 0; t < nk; ++t) {
        if (t + 1 < nk) {
            u16* buf = lds[(t + 1) & 1];
            const int k0 = (t + 1) << 5;
            gload16(A + a_src0 + k0, buf + tid * 8);
            gload16(A + a_src1 + k0, buf + tid * 8 + 4096);
            gload16(B + b_src + k0,  buf + tid * 8 + 8192);
            asm volatile("s_waitcnt vmcnt(3)" ::: "memory");
        } else {
            asm volatile("s_waitcnt vmcnt(0)" ::: "memory");
        }
        __builtin_amdgcn_s_barrier();
        asm volatile("" ::: "memory");
        const u16* As = lds[t & 1];
        const u16* Bs = lds[t & 1] + 8192;
        short8 af[4], bf[4];
        #pragma unroll
        for (int i = 0; i < 4; i++) {
            af[i] = *reinterpret_cast<const short8*>(&As[(wm + i * 16 + l16) * 32 + xq8]);
            bf[i] = *reinterpret_cast<const short8*>(&Bs[(wn + i * 16 + l16) * 32 + xq8]);
        }
        #pragma unroll
        for (int mi = 0; mi < 4; mi++)
            #pragma unroll
            for (int ni = 0; ni < 4; ni++)
                acc[mi][ni] = __builtin_amdgcn_mfma_f32_16x16x32_bf16(af[mi], bf[ni], acc[mi][ni], 0, 0, 0);
        asm volatile("" ::: "memory");
        __builtin_amdgcn_s_barrier();
    }

    if (EPI == 3) {
        float* ct = reinterpret_cast<float*>(&lds[0][0]) + wid * 1088;  // 16 x 68 f32
        const int rw = (lane >> 4) * 4;
        const int rr = lane >> 2;
        const int rc = (lane & 3) * 16;
        #pragma unroll
        for (int mi = 0; mi < 4; mi++) {
            asm volatile("" ::: "memory");
            #pragma unroll
            for (int ni = 0; ni < 4; ni++)
                #pragma unroll
                for (int j = 0; j < 4; j++)
                    ct[(rw + j) * 68 + ni * 16 + l16] = acc[mi][ni][j];
            asm volatile("" ::: "memory");
            const int m = m0 + wm + mi * 16 + rr;
            const int nb = n0 + wn + rc;
            float* crow = (float*)Cout + (size_t)m * ldc + nb;
            #pragma unroll
            for (int q = 0; q < 4; q++) {
                const f32x4 v = *reinterpret_cast<const f32x4*>(&ct[rr * 68 + rc + q * 4]);
                if (nb + q * 4 + 3 < N) {
                    *reinterpret_cast<f32x4*>(crow + q * 4) = v;
                } else {
                    #pragma unroll
                    for (int e = 0; e < 4; e++)
                        if (nb + q * 4 + e < N) crow[q * 4 + e] = v[e];
                }
            }
            asm volatile("" ::: "memory");
            __builtin_amdgcn_s_barrier();
        }
    } else {
        const int cb = n0 + wn + l16;
        const int rb = m0 + wm + (lane >> 4) * 4;
        #pragma unroll
        for (int ni = 0; ni < 4; ni++) {
            const int n = cb + ni * 16;
            const float bv = bias[n];
            #pragma unroll
            for (int mi = 0; mi < 4; mi++) {
                #pragma unroll
                for (int j = 0; j < 4; j++) {
                    const int m = rb + mi * 16 + j;
                    float v = acc[mi][ni][j] + bv;
                    if (EPI == 0) {
                        ((u16*)Cout)[(size_t)m * ldc + n] = f2bf(v);
                    } else {
                        const float t = tanhf(0.7978845608028654f * (v + 0.044715f * v * v * v));
                        ((u16*)Cout)[(size_t)m * ldc + n] = f2bf(0.5f * v * (1.f + t));
                    }
                }
            }
        }
    }
}

// ============ 128x128 2-phase split-K GEMM: resid += A*B^T + bias (atomicAdd) ======
// grid = ntiles * ksplit; block computes K-range [ks*Kp, ks*Kp+Kp).
__global__ __launch_bounds__(256) void gemm_splitk(
        const u16* __restrict__ A, int lda,
        const u16* __restrict__ B, int ldb,
        const float* __restrict__ bias,
        int ldc, int Kp, int nmt, int ntiles,
        float* __restrict__ resid) {
    __shared__ __align__(16) u16 lds[2][2][128 * 32];
    const int tid = threadIdx.x;
    const int lane = tid & 63, wid = tid >> 6;
    const int nwg = gridDim.x;
    const int o = blockIdx.x;
    const int wg = (o & 7) * (nwg >> 3) + (o >> 3);
    const int tile = wg % ntiles;
    const int ks = wg / ntiles;
    const int m0 = (tile % nmt) * 128, n0 = (tile / nmt) * 128;
    const int koff = ks * Kp;

    const int wm = (wid >> 1) * 64, wn = (wid & 1) * 64;
    const int l16 = lane & 15;
    const int qid = lane >> 4;
    const int xq8 = ((qid ^ (l16 & 3)) * 8);

    const int r0 = tid >> 2, q0 = (tid & 3) ^ (r0 & 3);
    const size_t a_src0 = (size_t)(m0 + r0) * lda + koff + q0 * 8;
    const size_t a_src1 = (size_t)(m0 + r0 + 64) * lda + koff + q0 * 8;
    const size_t b_src0 = (size_t)(n0 + r0) * ldb + koff + q0 * 8;
    const size_t b_src1 = (size_t)(n0 + r0 + 64) * ldb + koff + q0 * 8;

    f32x4 acc[4][4];
    #pragma unroll
    for (int i = 0; i < 4; i++)
        #pragma unroll
        for (int j = 0; j < 4; j++)
            acc[i][j] = (f32x4){0.f, 0.f, 0.f, 0.f};

    const int nk = Kp >> 5;
    gload16(A + a_src0, lds[0][0] + tid * 8);
    gload16(A + a_src1, lds[0][0] + tid * 8 + 2048);
    gload16(B + b_src0, lds[0][1] + tid * 8);
    gload16(B + b_src1, lds[0][1] + tid * 8 + 2048);

    for (int t = 0; t < nk; ++t) {
        if (t + 1 < nk) {
            u16* Ap = lds[(t + 1) & 1][0];
            u16* Bp = lds[(t + 1) & 1][1];
            const int k0 = (t + 1) << 5;
            gload16(A + a_src0 + k0, Ap + tid * 8);
            gload16(A + a_src1 + k0, Ap + tid * 8 + 2048);
            gload16(B + b_src0 + k0, Bp + tid * 8);
            gload16(B + b_src1 + k0, Bp + tid * 8 + 2048);
            asm volatile("s_waitcnt vmcnt(4)" ::: "memory");
        } else {
            asm volatile("s_waitcnt vmcnt(0)" ::: "memory");
        }
        __builtin_amdgcn_s_barrier();
        asm volatile("" ::: "memory");
        const u16* As = lds[t & 1][0];
        const u16* Bs = lds[t & 1][1];
        short8 af[4], bf[4];
        #pragma unroll
        for (int i = 0; i < 4; i++) {
            af[i] = *reinterpret_cast<const short8*>(&As[(wm + i * 16 + l16) * 32 + xq8]);
            bf[i] = *reinterpret_cast<const short8*>(&Bs[(wn + i * 16 + l16) * 32 + xq8]);
        }
        #pragma unroll
        for (int mi = 0; mi < 4; mi++)
            #pragma unroll
            for (int ni = 0; ni < 4; ni++)
                acc[mi][ni] = __builtin_amdgcn_mfma_f32_16x16x32_bf16(af[mi], bf[ni], acc[mi][ni], 0, 0, 0);
        asm volatile("" ::: "memory");
        __builtin_amdgcn_s_barrier();
    }

    const int cb = n0 + wn + l16;
    const int rb = m0 + wm + (lane >> 4) * 4;
    #pragma unroll
    for (int ni = 0; ni < 4; ni++) {
        const int n = cb + ni * 16;
        const float bv = (ks == 0) ? bias[n] : 0.f;
        #pragma unroll
        for (int mi = 0; mi < 4; mi++) {
            #pragma unroll
            for (int j = 0; j < 4; j++) {
                const int m = rb + mi * 16 + j;
                atomicAdd(&resid[(size_t)m * ldc + n], acc[mi][ni][j] + bv);
            }
        }
    }
}

// ---------------- fallback GEMM (B fp32, reg-staged) -- used only if ws too small ---
template<int EPI>
__global__ __launch_bounds__(256, 2) void gemm_bt(
        const u16* __restrict__ A, int lda,
        const float* __restrict__ B, int ldb,
        const float* __restrict__ bias,
        void* __restrict__ Cout, int ldc,
        int M, int N, int K,
        float* __restrict__ resid) {
    __shared__ __align__(16) u16 As[128][40];
    __shared__ __align__(16) u16 Bs[128][40];
    const int tid = threadIdx.x;
    const int lane = tid & 63, wid = tid >> 6;
    const int m0 = blockIdx.y * 128, n0 = blockIdx.x * 128;
    const int wm = (wid >> 1) * 64, wn = (wid & 1) * 64;
    const int l16 = lane & 15, lk = (lane >> 4) * 8;

    f32x4 acc[4][4];
    #pragma unroll
    for (int i = 0; i < 4; i++)
        #pragma unroll
        for (int j = 0; j < 4; j++)
            acc[i][j] = (f32x4){0.f, 0.f, 0.f, 0.f};

    for (int k0 = 0; k0 < K; k0 += 32) {
        #pragma unroll
        for (int p = 0; p < 2; p++) {
            const int e = p * 256 + tid;
            const int r = e >> 2, c = e & 3;
            uint4 v = *reinterpret_cast<const uint4*>(A + (size_t)(m0 + r) * lda + k0 + c * 8);
            *reinterpret_cast<uint4*>(&As[r][c * 8]) = v;
        }
        #pragma unroll
        for (int p = 0; p < 4; p++) {
            const int e = p * 256 + tid;
            const int r = e >> 3, c = e & 7;
            float4 v = make_float4(0.f, 0.f, 0.f, 0.f);
            if (n0 + r < N)
                v = *reinterpret_cast<const float4*>(B + (size_t)(n0 + r) * ldb + k0 + c * 4);
            ushort4 hv;
            hv.x = f2bf(v.x); hv.y = f2bf(v.y); hv.z = f2bf(v.z); hv.w = f2bf(v.w);
            *reinterpret_cast<ushort4*>(&Bs[r][c * 4]) = hv;
        }
        __syncthreads();
        short8 af[4], bfr[4];
        #pragma unroll
        for (int i = 0; i < 4; i++) {
            af[i]  = *reinterpret_cast<const short8*>(&As[wm + i * 16 + l16][lk]);
            bfr[i] = *reinterpret_cast<const short8*>(&Bs[wn + i * 16 + l16][lk]);
        }
        #pragma unroll
        for (int mi = 0; mi < 4; mi++)
            #pragma unroll
            for (int ni = 0; ni < 4; ni++)
                acc[mi][ni] = __builtin_amdgcn_mfma_f32_16x16x32_bf16(af[mi], bfr[ni], acc[mi][ni], 0, 0, 0);
        __syncthreads();
    }

    const int cb = n0 + wn + l16;
    const int rb = m0 + wm + (lane >> 4) * 4;
    #pragma unroll
    for (int ni = 0; ni < 4; ni++) {
        const int n = cb + ni * 16;
        if (n >= N) continue;
        float bv = 0.f;
        if (EPI != 3) bv = bias[n];
        #pragma unroll
        for (int mi = 0; mi < 4; mi++) {
            #pragma unroll
            for (int j = 0; j < 4; j++) {
                const int m = rb + mi * 16 + j;
                float v = acc[mi][ni][j] + bv;
                if (EPI == 0) {
                    ((u16*)Cout)[(size_t)m * ldc + n] = f2bf(v);
                } else if (EPI == 1) {
                    resid[(size_t)m * ldc + n] += v;
                } else if (EPI == 2) {
                    const float t = tanhf(0.7978845608028654f * (v + 0.044715f * v * v * v));
                    ((u16*)Cout)[(size_t)m * ldc + n] = f2bf(0.5f * v * (1.f + t));
                } else {
                    ((float*)Cout)[(size_t)m * ldc + n] = v;
                }
            }
        }
    }
}

// ---------------- MFMA flash attention, K/V double-buffer + async reg-stage -------
// One barrier per tile: writes at iter t target buf[(t+1)&1], whose last readers
// finished before barrier(t-1).  Global loads for t+1 issue before compute(t).
__global__ __launch_bounds__(256, 2) void attn_mfma_kernel(const u16* __restrict__ qkv,
                                                           u16* __restrict__ y) {
    __shared__ __align__(16) u16 Qs[64][72];
    __shared__ __align__(16) u16 Ks[2][64][72];
    __shared__ __align__(16) u16 Vt[2][64][72];  // transposed: Vt[.][d][s]
    __shared__ __align__(16) u16 Ps[4][16][72];  // per-wave P tile (bf16)

    const int tid = threadIdx.x;
    const int lane = tid & 63, wid = tid >> 6;
    const int l16 = lane & 15, lk = (lane >> 4) * 8;
    const int qt = blockIdx.x, h = blockIdx.y, b = blockIdx.z;

    const size_t base = (size_t)b * 1024 * 2304;
    const u16* qp = qkv + base + (size_t)(qt * 64) * 2304 + h * 64;
    const u16* kp = qkv + base + 768  + h * 64;
    const u16* vp = qkv + base + 1536 + h * 64;

    // staging coords (per thread, fixed):
    const int krr0 = tid >> 3, kc8_0 = tid & 7;           // K chunk e = tid
    const int krr1 = (tid + 256) >> 3, kc8_1 = tid & 7;   // K chunk e = tid + 256
    const int vs0 = (tid >> 4) * 2, vdq0 = tid & 15;      // V pair e = tid
    const int vs1 = ((tid + 256) >> 4) * 2, vdq1 = tid & 15;

    // ---- stage Q; load tile-0 K/V to regs ----
    #pragma unroll
    for (int p = 0; p < 2; p++) {
        const int e = p * 256 + tid;
        const int rr = e >> 3, c8 = e & 7;
        *reinterpret_cast<uint4*>(&Qs[rr][c8 * 8]) =
            *reinterpret_cast<const uint4*>(qp + (size_t)rr * 2304 + c8 * 8);
    }
    uint4 kreg0, kreg1; ushort4 vr0a, vr0b, vr1a, vr1b;
    kreg0 = *reinterpret_cast<const uint4*>(kp + (size_t)krr0 * 2304 + kc8_0 * 8);
    kreg1 = *reinterpret_cast<const uint4*>(kp + (size_t)krr1 * 2304 + kc8_1 * 8);
    vr0a = *reinterpret_cast<const ushort4*>(vp + (size_t)vs0 * 2304 + vdq0 * 4);
    vr0b = *reinterpret_cast<const ushort4*>(vp + (size_t)(vs0 + 1) * 2304 + vdq0 * 4);
    vr1a = *reinterpret_cast<const ushort4*>(vp + (size_t)vs1 * 2304 + vdq1 * 4);
    vr1b = *reinterpret_cast<const ushort4*>(vp + (size_t)(vs1 + 1) * 2304 + vdq1 * 4);
    __syncthreads();   // Qs ready

    short8 qf[2];
    #pragma unroll
    for (int kk = 0; kk < 2; kk++)
        qf[kk] = *reinterpret_cast<const short8*>(&Qs[wid * 16 + l16][kk * 32 + lk]);

    // write tile 0 into buf 0
    *reinterpret_cast<uint4*>(&Ks[0][krr0][kc8_0 * 8]) = kreg0;
    *reinterpret_cast<uint4*>(&Ks[0][krr1][kc8_1 * 8]) = kreg1;
    *reinterpret_cast<ushort2*>(&Vt[0][vdq0 * 4 + 0][vs0]) = make_ushort2(vr0a.x, vr0b.x);
    *reinterpret_cast<ushort2*>(&Vt[0][vdq0 * 4 + 1][vs0]) = make_ushort2(vr0a.y, vr0b.y);
    *reinterpret_cast<ushort2*>(&Vt[0][vdq0 * 4 + 2][vs0]) = make_ushort2(vr0a.z, vr0b.z);
    *reinterpret_cast<ushort2*>(&Vt[0][vdq0 * 4 + 3][vs0]) = make_ushort2(vr0a.w, vr0b.w);
    *reinterpret_cast<ushort2*>(&Vt[0][vdq1 * 4 + 0][vs1]) = make_ushort2(vr1a.x, vr1b.x);
    *reinterpret_cast<ushort2*>(&Vt[0][vdq1 * 4 + 1][vs1]) = make_ushort2(vr1a.y, vr1b.y);
    *reinterpret_cast<ushort2*>(&Vt[0][vdq1 * 4 + 2][vs1]) = make_ushort2(vr1a.z, vr1b.z);
    *reinterpret_cast<ushort2*>(&Vt[0][vdq1 * 4 + 3][vs1]) = make_ushort2(vr1a.w, vr1b.w);
    __syncthreads();   // tile 0 in LDS

    f32x4 o_acc[4];
    #pragma unroll
    for (int i = 0; i < 4; i++) o_acc[i] = (f32x4){0.f, 0.f, 0.f, 0.f};
    float l_part[4] = {0.f, 0.f, 0.f, 0.f};

    for (int t = 0; t < 16; ++t) {
        const int cur = t & 1, nxt = cur ^ 1;
        if (t + 1 < 16) {
            const int s0 = (t + 1) * 64;
            kreg0 = *reinterpret_cast<const uint4*>(kp + (size_t)(s0 + krr0) * 2304 + kc8_0 * 8);
            kreg1 = *reinterpret_cast<const uint4*>(kp + (size_t)(s0 + krr1) * 2304 + kc8_1 * 8);
            vr0a = *reinterpret_cast<const ushort4*>(vp + (size_t)(s0 + vs0) * 2304 + vdq0 * 4);
            vr0b = *reinterpret_cast<const ushort4*>(vp + (size_t)(s0 + vs0 + 1) * 2304 + vdq0 * 4);
            vr1a = *reinterpret_cast<const ushort4*>(vp + (size_t)(s0 + vs1) * 2304 + vdq1 * 4);
            vr1b = *reinterpret_cast<const ushort4*>(vp + (size_t)(s0 + vs1 + 1) * 2304 + vdq1 * 4);
        }

        // ---- S = Q K^T ----
        f32x4 sa[4];
        #pragma unroll
        for (int i = 0; i < 4; i++) sa[i] = (f32x4){0.f, 0.f, 0.f, 0.f};
        #pragma unroll
        for (int nj = 0; nj < 4; nj++) {
            #pragma unroll
            for (int kk = 0; kk < 2; kk++) {
                short8 kf = *reinterpret_cast<const short8*>(&Ks[cur][nj * 16 + l16][kk * 32 + lk]);
                sa[nj] = __builtin_amdgcn_mfma_f32_16x16x32_bf16(qf[kk], kf, sa[nj], 0, 0, 0);
            }
        }
        // ---- P = exp(S*scale), row sums, Ps(bf16) ----
        #pragma unroll
        for (int nj = 0; nj < 4; nj++) {
            #pragma unroll
            for (int r = 0; r < 4; r++) {
                const float pv = __expf(sa[nj][r] * 0.125f);
                l_part[r] += pv;
                Ps[wid][(lane >> 4) * 4 + r][nj * 16 + l16] = f2bf(pv);
            }
        }
        // ---- O += P V ----
        short8 pa[2];
        #pragma unroll
        for (int kk = 0; kk < 2; kk++)
            pa[kk] = *reinterpret_cast<const short8*>(&Ps[wid][l16][kk * 32 + lk]);
        #pragma unroll
        for (int nd = 0; nd < 4; nd++) {
            #pragma unroll
            for (int kk = 0; kk < 2; kk++) {
                short8 vf = *reinterpret_cast<const short8*>(&Vt[cur][nd * 16 + l16][kk * 32 + lk]);
                o_acc[nd] = __builtin_amdgcn_mfma_f32_16x16x32_bf16(pa[kk], vf, o_acc[nd], 0, 0, 0);
            }
        }

        if (t + 1 < 16) {
            *reinterpret_cast<uint4*>(&Ks[nxt][krr0][kc8_0 * 8]) = kreg0;
            *reinterpret_cast<uint4*>(&Ks[nxt][krr1][kc8_1 * 8]) = kreg1;
            *reinterpret_cast<ushort2*>(&Vt[nxt][vdq0 * 4 + 0][vs0]) = make_ushort2(vr0a.x, vr0b.x);
            *reinterpret_cast<ushort2*>(&Vt[nxt][vdq0 * 4 + 1][vs0]) = make_ushort2(vr0a.y, vr0b.y);
            *reinterpret_cast<ushort2*>(&Vt[nxt][vdq0 * 4 + 2][vs0]) = make_ushort2(vr0a.z, vr0b.z);
            *reinterpret_cast<ushort2*>(&Vt[nxt][vdq0 * 4 + 3][vs0]) = make_ushort2(vr0a.w, vr0b.w);
            *reinterpret_cast<ushort2*>(&Vt[nxt][vdq1 * 4 + 0][vs1]) = make_ushort2(vr1a.x, vr1b.x);
            *reinterpret_cast<ushort2*>(&Vt[nxt][vdq1 * 4 + 1][vs1]) = make_ushort2(vr1a.y, vr1b.y);
            *reinterpret_cast<ushort2*>(&Vt[nxt][vdq1 * 4 + 2][vs1]) = make_ushort2(vr1a.z, vr1b.z);
            *reinterpret_cast<ushort2*>(&Vt[nxt][vdq1 * 4 + 3][vs1]) = make_ushort2(vr1a.w, vr1b.w);
        }
        __syncthreads();
    }

    float inv[4];
    #pragma unroll
    for (int r = 0; r < 4; r++) {
        float s = l_part[r];
        #pragma unroll
        for (int off = 8; off >= 1; off >>= 1) s += __shfl_xor(s, off);
        inv[r] = 1.f / s;
    }
    const int rowb = b * 1024 + qt * 64 + wid * 16 + (lane >> 4) * 4;
    #pragma unroll
    for (int nd = 0; nd < 4; nd++) {
        const int col = h * 64 + nd * 16 + l16;
        #pragma unroll
        for (int r = 0; r < 4; r++) {
            y[(size_t)(rowb + r) * 768 + col] = f2bf(o_acc[nd][r] * inv[r]);
        }
    }
}

// ---------------- driver ----------------
extern "C" void kernel_launch(void* const* d_in, const int* in_sizes, int n_in,
                              void* d_out, int out_size, void* d_ws, size_t ws_size,
                              hipStream_t stream) {
    (void)in_sizes; (void)n_in; (void)out_size;
    const int*   idx    = (const int*)d_in[0];
    const float* wte    = (const float*)d_in[1];
    const float* wpe    = (const float*)d_in[2];
    const float* ln1w   = (const float*)d_in[3];
    const float* ln1b   = (const float*)d_in[4];
    const float* attnw  = (const float*)d_in[5];
    const float* attnb  = (const float*)d_in[6];
    const float* projw  = (const float*)d_in[7];
    const float* projb  = (const float*)d_in[8];
    const float* ln2w   = (const float*)d_in[9];
    const float* ln2b   = (const float*)d_in[10];
    const float* fcw    = (const float*)d_in[11];
    const float* fcb    = (const float*)d_in[12];
    const float* mprojw = (const float*)d_in[13];
    const float* mprojb = (const float*)d_in[14];
    const float* lnfw   = (const float*)d_in[15];
    const float* lnfb   = (const float*)d_in[16];
    const float* lmw    = (const float*)d_in[17];
    float* out = (float*)d_out;

    // ---- workspace layout ----
    char* p = (char*)d_ws;
    size_t used = 0;
    auto take = [&](size_t bytes) { char* q = p + used; used += (bytes + 255) & ~(size_t)255; return q; };
    float* x      = (float*)take((size_t)4096 * 768 * 4);
    u16*   a_bf   = (u16*)take((size_t)4096 * 768 * 2);
    u16*   qkv_bf = (u16*)take((size_t)4096 * 2304 * 2);
    u16*   hid_bf = (u16*)take((size_t)4096 * 3072 * 2);
    u16*   w_lm   = (u16*)take((size_t)30592 * 768 * 2);
    const bool castLm = used <= ws_size;
    u16*   w_attn = (u16*)take((size_t)12 * 2304 * 768 * 2);
    u16*   w_proj = (u16*)take((size_t)12 * 768 * 768 * 2);
    u16*   w_fc   = (u16*)take((size_t)12 * 3072 * 768 * 2);
    u16*   w_mprj = (u16*)take((size_t)12 * 768 * 3072 * 2);
    const bool castAll = used <= ws_size;

    embed_kernel<<<4096, 256, 0, stream>>>(idx, wte, wpe, x);

    if (castLm)
        castw_kernel<<<2048, 256, 0, stream>>>(lmw, w_lm, (long)30522 * 768, (long)30592 * 768);
    if (castAll) {
        castw_kernel<<<2048, 256, 0, stream>>>(attnw,  w_attn, (long)12 * 2304 * 768, (long)12 * 2304 * 768);
        castw_kernel<<<2048, 256, 0, stream>>>(projw,  w_proj, (long)12 * 768 * 768,  (long)12 * 768 * 768);
        castw_kernel<<<2048, 256, 0, stream>>>(fcw,    w_fc,   (long)12 * 3072 * 768, (long)12 * 3072 * 768);
        castw_kernel<<<2048, 256, 0, stream>>>(mprojw, w_mprj, (long)12 * 768 * 3072, (long)12 * 768 * 3072);
    }

    for (int l = 0; l < 12; l++) {
        ln_kernel<<<1024, 256, 0, stream>>>(x, ln1w + l * 768, ln1b + l * 768, a_bf);
        if (castAll) {
            gemm_big<0, 0><<<16 * 18, 512, 0, stream>>>(
                a_bf, 768, w_attn + (size_t)l * 2304 * 768, 768, attnb + l * 2304,
                (void*)qkv_bf, 2304, 2304, 768, 16);
        } else {
            gemm_bt<0><<<dim3(18, 32), 256, 0, stream>>>(
                a_bf, 768, attnw + (size_t)l * 2304 * 768, 768, attnb + l * 2304,
                (void*)qkv_bf, 2304, 4096, 2304, 768, nullptr);
        }
        attn_mfma_kernel<<<dim3(16, 12, 4), 256, 0, stream>>>(qkv_bf, a_bf);
        if (castAll) {
            gemm_splitk<<<192 * 2, 256, 0, stream>>>(
                a_bf, 768, w_proj + (size_t)l * 768 * 768, 768, projb + l * 768,
                768, 384, 32, 192, x);
        } else {
            gemm_bt<1><<<dim3(6, 32), 256, 0, stream>>>(
                a_bf, 768, projw + (size_t)l * 768 * 768, 768, projb + l * 768,
                nullptr, 768, 4096, 768, 768, x);
        }
        ln_kernel<<<1024, 256, 0, stream>>>(x, ln2w + l * 768, ln2b + l * 768, a_bf);
        if (castAll) {
            gemm_big<2, 0><<<16 * 24, 512, 0, stream>>>(
                a_bf, 768, w_fc + (size_t)l * 3072 * 768, 768, fcb + l * 3072,
                (void*)hid_bf, 3072, 3072, 768, 16);
            gemm_splitk<<<192 * 4, 256, 0, stream>>>(
                hid_bf, 3072, w_mprj + (size_t)l * 768 * 3072, 3072, mprojb + l * 768,
                768, 768, 32, 192, x);
        } else {
            gemm_bt<2><<<dim3(24, 32), 256, 0, stream>>>(
                a_bf, 768, fcw + (size_t)l * 3072 * 768, 768, fcb + l * 3072,
                (void*)hid_bf, 3072, 4096, 3072, 768, nullptr);
            gemm_bt<1><<<dim3(6, 32), 256, 0, stream>>>(
                hid_bf, 3072, mprojw + (size_t)l * 768 * 3072, 3072, mprojb + l * 768,
                nullptr, 768, 4096, 768, 3072, x);
        }
    }

    ln_kernel<<<1024, 256, 0, stream>>>(x, lnfw, lnfb, a_bf);
    if (castLm) {
        gemm_big<3, 1><<<16 * 239, 512, 0, stream>>>(
            a_bf, 768, w_lm, 768, nullptr, (void*)out, 30522, 30522, 768, 239);
    } else {
        gemm_bt<3><<<dim3(239, 32), 256, 0, stream>>>(
            a_bf, 768, lmw, 768, nullptr, (void*)out, 30522, 4096, 30522, 768, nullptr);
    }
}

// Round 10
// 2995.734 us; speedup vs baseline: 1.0144x; 1.0144x over previous
//
#include <hip/hip_runtime.h>
#include <hip/hip_bf16.h>
#include <math.h>

// ---------------- types & helpers ----------------
typedef __attribute__((ext_vector_type(8))) short short8;   // 8 x bf16 (4 VGPRs)
typedef __attribute__((ext_vector_type(4))) float f32x4;

typedef unsigned short u16;

__device__ __forceinline__ u16 f2bf(float f) {
    union { float f; unsigned int u; } v; v.f = f;
    unsigned int u = v.u;
    unsigned int r = (u + 0x7fffu + ((u >> 16) & 1u)) >> 16;  // RNE
    return (u16)r;
}
__device__ __forceinline__ float bf2f(u16 u) {
    union { unsigned int u; float f; } v; v.u = ((unsigned int)u) << 16;
    return v.f;
}

// async global->LDS 16B copy (wave base + lane*16 dest, per-lane global src).
__device__ __forceinline__ void gload16(const void* g, void* l) {
    __builtin_amdgcn_global_load_lds(
        (const __attribute__((address_space(1))) void*)g,
        (__attribute__((address_space(3))) void*)l, 16, 0, 0);
}

// ---------------- weight cast: f32 -> bf16 (pad region zeroed) ----------------
__global__ __launch_bounds__(256) void castw_kernel(const float* __restrict__ src,
                                                    u16* __restrict__ dst,
                                                    long n, long npad) {
    long i = ((long)blockIdx.x * 256 + threadIdx.x) * 4;
    const long stride = (long)gridDim.x * 1024;
    for (; i < npad; i += stride) {
        ushort4 o;
        if (i < n) {
            float4 v = *reinterpret_cast<const float4*>(src + i);
            o.x = f2bf(v.x); o.y = f2bf(v.y); o.z = f2bf(v.z); o.w = f2bf(v.w);
        } else {
            o = make_ushort4(0, 0, 0, 0);
        }
        *reinterpret_cast<ushort4*>(dst + i) = o;
    }
}

// ---------------- embed: x = wte[idx] + wpe[t] ----------------
__global__ __launch_bounds__(256) void embed_kernel(const int* __restrict__ idx,
                                                    const float* __restrict__ wte,
                                                    const float* __restrict__ wpe,
                                                    float* __restrict__ x) {
    const int row = blockIdx.x;            // b*1024 + t
    const int tid = threadIdx.x;
    const int t = row & 1023;
    const int tok = idx[row];
    const float* we = wte + (size_t)tok * 768;
    const float* pe = wpe + (size_t)t * 768;
    float* xr = x + (size_t)row * 768;
    xr[tid]       = we[tid]       + pe[tid];
    xr[tid + 256] = we[tid + 256] + pe[tid + 256];
    xr[tid + 512] = we[tid + 512] + pe[tid + 512];
}

// ---------------- LayerNorm: wave-per-row (no LDS, no barriers) ----------------
__global__ __launch_bounds__(256) void ln_kernel(const float* __restrict__ x,
                                                 const float* __restrict__ w,
                                                 const float* __restrict__ b,
                                                 u16* __restrict__ out) {
    const int wid = threadIdx.x >> 6, lane = threadIdx.x & 63;
    const int row = blockIdx.x * 4 + wid;
    const float* xr = x + (size_t)row * 768;
    const float4 v0 = *reinterpret_cast<const float4*>(xr + lane * 4);
    const float4 v1 = *reinterpret_cast<const float4*>(xr + 256 + lane * 4);
    const float4 v2 = *reinterpret_cast<const float4*>(xr + 512 + lane * 4);
    float s = v0.x + v0.y + v0.z + v0.w + v1.x + v1.y + v1.z + v1.w
            + v2.x + v2.y + v2.z + v2.w;
    float q = v0.x * v0.x + v0.y * v0.y + v0.z * v0.z + v0.w * v0.w
            + v1.x * v1.x + v1.y * v1.y + v1.z * v1.z + v1.w * v1.w
            + v2.x * v2.x + v2.y * v2.y + v2.z * v2.z + v2.w * v2.w;
    #pragma unroll
    for (int off = 32; off >= 1; off >>= 1) {
        s += __shfl_xor(s, off);
        q += __shfl_xor(q, off);
    }
    const float mean = s * (1.f / 768.f);
    const float var = q * (1.f / 768.f) - mean * mean;
    const float rstd = rsqrtf(var + 1e-5f);
    u16* orow = out + (size_t)row * 768;
    #pragma unroll
    for (int seg = 0; seg < 3; seg++) {
        const float4 v = seg == 0 ? v0 : (seg == 1 ? v1 : v2);
        const float4 wv = *reinterpret_cast<const float4*>(w + seg * 256 + lane * 4);
        const float4 bv = *reinterpret_cast<const float4*>(b + seg * 256 + lane * 4);
        ushort4 ov;
        ov.x = f2bf((v.x - mean) * rstd * wv.x + bv.x);
        ov.y = f2bf((v.y - mean) * rstd * wv.y + bv.y);
        ov.z = f2bf((v.z - mean) * rstd * wv.z + bv.z);
        ov.w = f2bf((v.w - mean) * rstd * wv.w + bv.w);
        *reinterpret_cast<ushort4*>(orow + seg * 256 + lane * 4) = ov;
    }
}

// =========== 256x128-tile 2-phase GEMM, 512 threads ==================
// C[m,n] = sum_k A[m,k]*B[n,k].  BM=256, BN=128, BK=32.  8 waves = 4M x 2N.
// 2-phase dbuf, counted vmcnt(3).  LDS quarter-swizzle q' = q ^ ((row>>1)&3)
// applied to gload SOURCE + ds_read offset (LDS dest linear, rule #21):
// spreads a wave's 16-row b128 reads over 8 bank-spans -> 2-way (free).
// ORDER: 0 = m-fastest, 1 = n-fastest.  nmt = tile count of the FAST dim.
// EPI: 0 = +bias -> bf16; 2 = +bias+GELU -> bf16; 3 = plain f32 (n<N guard,
//      stride-76 LDS transpose + float4 stores)
template<int EPI, int ORDER>
__global__ __launch_bounds__(512) void gemm_big(
        const u16* __restrict__ A, int lda,
        const u16* __restrict__ B, int ldb,
        const float* __restrict__ bias,
        void* __restrict__ Cout, int ldc,
        int N, int K, int nmt) {
    __shared__ __align__(16) u16 lds[2][384 * 32];   // [buf]: A = [0,8192) u16, B = [8192,12288)
    const int tid = threadIdx.x;
    const int lane = tid & 63, wid = tid >> 6;
    const int nwg = gridDim.x;
    const int o = blockIdx.x;
    const int wg = (o & 7) * (nwg >> 3) + (o >> 3);   // bijective XCD swizzle (grid%8==0)
    int m0, n0;
    if (ORDER == 0) { m0 = (wg % nmt) * 256; n0 = (wg / nmt) * 128; }
    else            { n0 = (wg % nmt) * 128; m0 = (wg / nmt) * 256; }

    const int wm = (wid >> 1) * 64, wn = (wid & 1) * 64;
    const int l16 = lane & 15;
    const int qid = lane >> 4;
    const int xq8 = ((qid ^ ((l16 >> 1) & 3)) * 8);   // swizzled read quarter

    const int ar = tid >> 2, aq = (tid & 3) ^ ((ar >> 1) & 3);
    const size_t a_src0 = (size_t)(m0 + ar) * lda + aq * 8;
    const size_t a_src1 = (size_t)(m0 + ar + 128) * lda + aq * 8;
    const size_t b_src = (size_t)(n0 + ar) * ldb + aq * 8;

    f32x4 acc[4][4];
    #pragma unroll
    for (int i = 0; i < 4; i++)
        #pragma unroll
        for (int j = 0; j < 4; j++)
            acc[i][j] = (f32x4){0.f, 0.f, 0.f, 0.f};

    const int nk = K >> 5;
    gload16(A + a_src0, lds[0] + tid * 8);
    gload16(A + a_src1, lds[0] + tid * 8 + 4096);
    gload16(B + b_src,  lds[0] + tid * 8 + 8192);

    for (int t = 0; t < nk; ++t) {
        if (t + 1 < nk) {
            u16* buf = lds[(t + 1) & 1];
            const int k0 = (t + 1) << 5;
            gload16(A + a_src0 + k0, buf + tid * 8);
            gload16(A + a_src1 + k0, buf + tid * 8 + 4096);
            gload16(B + b_src + k0,  buf + tid * 8 + 8192);
            asm volatile("s_waitcnt vmcnt(3)" ::: "memory");
        } else {
            asm volatile("s_waitcnt vmcnt(0)" ::: "memory");
        }
        __builtin_amdgcn_s_barrier();
        asm volatile("" ::: "memory");
        const u16* As = lds[t & 1];
        const u16* Bs = lds[t & 1] + 8192;
        short8 af[4], bf[4];
        #pragma unroll
        for (int i = 0; i < 4; i++) {
            af[i] = *reinterpret_cast<const short8*>(&As[(wm + i * 16 + l16) * 32 + xq8]);
            bf[i] = *reinterpret_cast<const short8*>(&Bs[(wn + i * 16 + l16) * 32 + xq8]);
        }
        #pragma unroll
        for (int mi = 0; mi < 4; mi++)
            #pragma unroll
            for (int ni = 0; ni < 4; ni++)
                acc[mi][ni] = __builtin_amdgcn_mfma_f32_16x16x32_bf16(af[mi], bf[ni], acc[mi][ni], 0, 0, 0);
        asm volatile("" ::: "memory");
        __builtin_amdgcn_s_barrier();
    }

    if (EPI == 3) {
        float* ct = reinterpret_cast<float*>(&lds[0][0]) + wid * 1216;  // 16 x 76 f32
        const int rw = (lane >> 4) * 4;
        const int rr = lane >> 2;
        const int rc = (lane & 3) * 16;
        #pragma unroll
        for (int mi = 0; mi < 4; mi++) {
            asm volatile("" ::: "memory");
            #pragma unroll
            for (int ni = 0; ni < 4; ni++)
                #pragma unroll
                for (int j = 0; j < 4; j++)
                    ct[(rw + j) * 76 + ni * 16 + l16] = acc[mi][ni][j];
            asm volatile("" ::: "memory");
            const int m = m0 + wm + mi * 16 + rr;
            const int nb = n0 + wn + rc;
            float* crow = (float*)Cout + (size_t)m * ldc + nb;
            #pragma unroll
            for (int q = 0; q < 4; q++) {
                const f32x4 v = *reinterpret_cast<const f32x4*>(&ct[rr * 76 + rc + q * 4]);
                if (nb + q * 4 + 3 < N) {
                    *reinterpret_cast<f32x4*>(crow + q * 4) = v;
                } else {
                    #pragma unroll
                    for (int e = 0; e < 4; e++)
                        if (nb + q * 4 + e < N) crow[q * 4 + e] = v[e];
                }
            }
            asm volatile("" ::: "memory");
            __builtin_amdgcn_s_barrier();
        }
    } else {
        const int cb = n0 + wn + l16;
        const int rb = m0 + wm + (lane >> 4) * 4;
        #pragma unroll
        for (int ni = 0; ni < 4; ni++) {
            const int n = cb + ni * 16;
            const float bv = bias[n];
            #pragma unroll
            for (int mi = 0; mi < 4; mi++) {
                #pragma unroll
                for (int j = 0; j < 4; j++) {
                    const int m = rb + mi * 16 + j;
                    float v = acc[mi][ni][j] + bv;
                    if (EPI == 0) {
                        ((u16*)Cout)[(size_t)m * ldc + n] = f2bf(v);
                    } else {
                        const float t = tanhf(0.7978845608028654f * (v + 0.044715f * v * v * v));
                        ((u16*)Cout)[(size_t)m * ldc + n] = f2bf(0.5f * v * (1.f + t));
                    }
                }
            }
        }
    }
}

// ============ 128x128 2-phase split-K GEMM: resid += A*B^T + bias (atomicAdd) ======
// grid = ntiles * ksplit; block computes K-range [ks*Kp, ks*Kp+Kp).
__global__ __launch_bounds__(256) void gemm_splitk(
        const u16* __restrict__ A, int lda,
        const u16* __restrict__ B, int ldb,
        const float* __restrict__ bias,
        int ldc, int Kp, int nmt, int ntiles,
        float* __restrict__ resid) {
    __shared__ __align__(16) u16 lds[2][2][128 * 32];
    const int tid = threadIdx.x;
    const int lane = tid & 63, wid = tid >> 6;
    const int nwg = gridDim.x;
    const int o = blockIdx.x;
    const int wg = (o & 7) * (nwg >> 3) + (o >> 3);
    const int tile = wg % ntiles;
    const int ks = wg / ntiles;
    const int m0 = (tile % nmt) * 128, n0 = (tile / nmt) * 128;
    const int koff = ks * Kp;

    const int wm = (wid >> 1) * 64, wn = (wid & 1) * 64;
    const int l16 = lane & 15;
    const int qid = lane >> 4;
    const int xq8 = ((qid ^ ((l16 >> 1) & 3)) * 8);

    const int r0 = tid >> 2, q0 = (tid & 3) ^ ((r0 >> 1) & 3);
    const size_t a_src0 = (size_t)(m0 + r0) * lda + koff + q0 * 8;
    const size_t a_src1 = (size_t)(m0 + r0 + 64) * lda + koff + q0 * 8;
    const size_t b_src0 = (size_t)(n0 + r0) * ldb + koff + q0 * 8;
    const size_t b_src1 = (size_t)(n0 + r0 + 64) * ldb + koff + q0 * 8;

    f32x4 acc[4][4];
    #pragma unroll
    for (int i = 0; i < 4; i++)
        #pragma unroll
        for (int j = 0; j < 4; j++)
            acc[i][j] = (f32x4){0.f, 0.f, 0.f, 0.f};

    const int nk = Kp >> 5;
    gload16(A + a_src0, lds[0][0] + tid * 8);
    gload16(A + a_src1, lds[0][0] + tid * 8 + 2048);
    gload16(B + b_src0, lds[0][1] + tid * 8);
    gload16(B + b_src1, lds[0][1] + tid * 8 + 2048);

    for (int t = 0; t < nk; ++t) {
        if (t + 1 < nk) {
            u16* Ap = lds[(t + 1) & 1][0];
            u16* Bp = lds[(t + 1) & 1][1];
            const int k0 = (t + 1) << 5;
            gload16(A + a_src0 + k0, Ap + tid * 8);
            gload16(A + a_src1 + k0, Ap + tid * 8 + 2048);
            gload16(B + b_src0 + k0, Bp + tid * 8);
            gload16(B + b_src1 + k0, Bp + tid * 8 + 2048);
            asm volatile("s_waitcnt vmcnt(4)" ::: "memory");
        } else {
            asm volatile("s_waitcnt vmcnt(0)" ::: "memory");
        }
        __builtin_amdgcn_s_barrier();
        asm volatile("" ::: "memory");
        const u16* As = lds[t & 1][0];
        const u16* Bs = lds[t & 1][1];
        short8 af[4], bf[4];
        #pragma unroll
        for (int i = 0; i < 4; i++) {
            af[i] = *reinterpret_cast<const short8*>(&As[(wm + i * 16 + l16) * 32 + xq8]);
            bf[i] = *reinterpret_cast<const short8*>(&Bs[(wn + i * 16 + l16) * 32 + xq8]);
        }
        #pragma unroll
        for (int mi = 0; mi < 4; mi++)
            #pragma unroll
            for (int ni = 0; ni < 4; ni++)
                acc[mi][ni] = __builtin_amdgcn_mfma_f32_16x16x32_bf16(af[mi], bf[ni], acc[mi][ni], 0, 0, 0);
        asm volatile("" ::: "memory");
        __builtin_amdgcn_s_barrier();
    }

    const int cb = n0 + wn + l16;
    const int rb = m0 + wm + (lane >> 4) * 4;
    #pragma unroll
    for (int ni = 0; ni < 4; ni++) {
        const int n = cb + ni * 16;
        const float bv = (ks == 0) ? bias[n] : 0.f;
        #pragma unroll
        for (int mi = 0; mi < 4; mi++) {
            #pragma unroll
            for (int j = 0; j < 4; j++) {
                const int m = rb + mi * 16 + j;
                atomicAdd(&resid[(size_t)m * ldc + n], acc[mi][ni][j] + bv);
            }
        }
    }
}

// ---------------- fallback GEMM (B fp32, reg-staged) -- used only if ws too small ---
template<int EPI>
__global__ __launch_bounds__(256, 2) void gemm_bt(
        const u16* __restrict__ A, int lda,
        const float* __restrict__ B, int ldb,
        const float* __restrict__ bias,
        void* __restrict__ Cout, int ldc,
        int M, int N, int K,
        float* __restrict__ resid) {
    __shared__ __align__(16) u16 As[128][40];
    __shared__ __align__(16) u16 Bs[128][40];
    const int tid = threadIdx.x;
    const int lane = tid & 63, wid = tid >> 6;
    const int m0 = blockIdx.y * 128, n0 = blockIdx.x * 128;
    const int wm = (wid >> 1) * 64, wn = (wid & 1) * 64;
    const int l16 = lane & 15, lk = (lane >> 4) * 8;

    f32x4 acc[4][4];
    #pragma unroll
    for (int i = 0; i < 4; i++)
        #pragma unroll
        for (int j = 0; j < 4; j++)
            acc[i][j] = (f32x4){0.f, 0.f, 0.f, 0.f};

    for (int k0 = 0; k0 < K; k0 += 32) {
        #pragma unroll
        for (int p = 0; p < 2; p++) {
            const int e = p * 256 + tid;
            const int r = e >> 2, c = e & 3;
            uint4 v = *reinterpret_cast<const uint4*>(A + (size_t)(m0 + r) * lda + k0 + c * 8);
            *reinterpret_cast<uint4*>(&As[r][c * 8]) = v;
        }
        #pragma unroll
        for (int p = 0; p < 4; p++) {
            const int e = p * 256 + tid;
            const int r = e >> 3, c = e & 7;
            float4 v = make_float4(0.f, 0.f, 0.f, 0.f);
            if (n0 + r < N)
                v = *reinterpret_cast<const float4*>(B + (size_t)(n0 + r) * ldb + k0 + c * 4);
            ushort4 hv;
            hv.x = f2bf(v.x); hv.y = f2bf(v.y); hv.z = f2bf(v.z); hv.w = f2bf(v.w);
            *reinterpret_cast<ushort4*>(&Bs[r][c * 4]) = hv;
        }
        __syncthreads();
        short8 af[4], bfr[4];
        #pragma unroll
        for (int i = 0; i < 4; i++) {
            af[i]  = *reinterpret_cast<const short8*>(&As[wm + i * 16 + l16][lk]);
            bfr[i] = *reinterpret_cast<const short8*>(&Bs[wn + i * 16 + l16][lk]);
        }
        #pragma unroll
        for (int mi = 0; mi < 4; mi++)
            #pragma unroll
            for (int ni = 0; ni < 4; ni++)
                acc[mi][ni] = __builtin_amdgcn_mfma_f32_16x16x32_bf16(af[mi], bfr[ni], acc[mi][ni], 0, 0, 0);
        __syncthreads();
    }

    const int cb = n0 + wn + l16;
    const int rb = m0 + wm + (lane >> 4) * 4;
    #pragma unroll
    for (int ni = 0; ni < 4; ni++) {
        const int n = cb + ni * 16;
        if (n >= N) continue;
        float bv = 0.f;
        if (EPI != 3) bv = bias[n];
        #pragma unroll
        for (int mi = 0; mi < 4; mi++) {
            #pragma unroll
            for (int j = 0; j < 4; j++) {
                const int m = rb + mi * 16 + j;
                float v = acc[mi][ni][j] + bv;
                if (EPI == 0) {
                    ((u16*)Cout)[(size_t)m * ldc + n] = f2bf(v);
                } else if (EPI == 1) {
                    resid[(size_t)m * ldc + n] += v;
                } else if (EPI == 2) {
                    const float t = tanhf(0.7978845608028654f * (v + 0.044715f * v * v * v));
                    ((u16*)Cout)[(size_t)m * ldc + n] = f2bf(0.5f * v * (1.f + t));
                } else {
                    ((float*)Cout)[(size_t)m * ldc + n] = v;
                }
            }
        }
    }
}

// ---------------- MFMA flash attention: QBLK=128, 512 threads, K/V dbuf -----------
// 8 waves; wave w owns q-rows w*16..w*16+15.  One barrier per KV-tile; global
// loads for tile t+1 issue (regs) before compute(t), LDS-write after (T14).
__global__ __launch_bounds__(512, 2) void attn_mfma_kernel(const u16* __restrict__ qkv,
                                                           u16* __restrict__ y) {
    __shared__ __align__(16) u16 Qs[128][72];
    __shared__ __align__(16) u16 Ks[2][64][72];
    __shared__ __align__(16) u16 Vt[2][64][72];  // transposed: Vt[.][d][s]
    __shared__ __align__(16) u16 Ps[8][16][72];  // per-wave P tile (bf16)

    const int tid = threadIdx.x;
    const int lane = tid & 63, wid = tid >> 6;
    const int l16 = lane & 15, lk = (lane >> 4) * 8;
    const int qt = blockIdx.x, h = blockIdx.y, b = blockIdx.z;

    const size_t base = (size_t)b * 1024 * 2304;
    const u16* qp = qkv + base + (size_t)(qt * 128) * 2304 + h * 64;
    const u16* kp = qkv + base + 768  + h * 64;
    const u16* vp = qkv + base + 1536 + h * 64;

    // staging coords (per thread, fixed): one K chunk + one V row-pair each
    const int krr = tid >> 3, kc8 = tid & 7;       // K: 64 rows x 8 chunks = 512
    const int vs = (tid >> 4) * 2, vdq = tid & 15; // V: 32 row-pairs x 16 dq = 512

    // ---- stage Q (128 x 64); load tile-0 K/V to regs ----
    #pragma unroll
    for (int p = 0; p < 2; p++) {
        const int e = p * 512 + tid;
        const int rr = e >> 3, c8 = e & 7;
        *reinterpret_cast<uint4*>(&Qs[rr][c8 * 8]) =
            *reinterpret_cast<const uint4*>(qp + (size_t)rr * 2304 + c8 * 8);
    }
    uint4 kreg; ushort4 vra, vrb;
    kreg = *reinterpret_cast<const uint4*>(kp + (size_t)krr * 2304 + kc8 * 8);
    vra = *reinterpret_cast<const ushort4*>(vp + (size_t)vs * 2304 + vdq * 4);
    vrb = *reinterpret_cast<const ushort4*>(vp + (size_t)(vs + 1) * 2304 + vdq * 4);
    __syncthreads();   // Qs ready

    short8 qf[2];
    #pragma unroll
    for (int kk = 0; kk < 2; kk++)
        qf[kk] = *reinterpret_cast<const short8*>(&Qs[wid * 16 + l16][kk * 32 + lk]);

    // write tile 0 into buf 0
    *reinterpret_cast<uint4*>(&Ks[0][krr][kc8 * 8]) = kreg;
    *reinterpret_cast<ushort2*>(&Vt[0][vdq * 4 + 0][vs]) = make_ushort2(vra.x, vrb.x);
    *reinterpret_cast<ushort2*>(&Vt[0][vdq * 4 + 1][vs]) = make_ushort2(vra.y, vrb.y);
    *reinterpret_cast<ushort2*>(&Vt[0][vdq * 4 + 2][vs]) = make_ushort2(vra.z, vrb.z);
    *reinterpret_cast<ushort2*>(&Vt[0][vdq * 4 + 3][vs]) = make_ushort2(vra.w, vrb.w);
    __syncthreads();   // tile 0 in LDS

    f32x4 o_acc[4];
    #pragma unroll
    for (int i = 0; i < 4; i++) o_acc[i] = (f32x4){0.f, 0.f, 0.f, 0.f};
    float l_part[4] = {0.f, 0.f, 0.f, 0.f};

    for (int t = 0; t < 16; ++t) {
        const int cur = t & 1, nxt = cur ^ 1;
        if (t + 1 < 16) {
            const int s0 = (t + 1) * 64;
            kreg = *reinterpret_cast<const uint4*>(kp + (size_t)(s0 + krr) * 2304 + kc8 * 8);
            vra = *reinterpret_cast<const ushort4*>(vp + (size_t)(s0 + vs) * 2304 + vdq * 4);
            vrb = *reinterpret_cast<const ushort4*>(vp + (size_t)(s0 + vs + 1) * 2304 + vdq * 4);
        }

        // ---- S = Q K^T (16 x 64 per wave) ----
        f32x4 sa[4];
        #pragma unroll
        for (int i = 0; i < 4; i++) sa[i] = (f32x4){0.f, 0.f, 0.f, 0.f};
        #pragma unroll
        for (int nj = 0; nj < 4; nj++) {
            #pragma unroll
            for (int kk = 0; kk < 2; kk++) {
                short8 kf = *reinterpret_cast<const short8*>(&Ks[cur][nj * 16 + l16][kk * 32 + lk]);
                sa[nj] = __builtin_amdgcn_mfma_f32_16x16x32_bf16(qf[kk], kf, sa[nj], 0, 0, 0);
            }
        }
        // ---- P = exp(S*scale), row sums, Ps(bf16) ----
        #pragma unroll
        for (int nj = 0; nj < 4; nj++) {
            #pragma unroll
            for (int r = 0; r < 4; r++) {
                const float pv = __expf(sa[nj][r] * 0.125f);
                l_part[r] += pv;
                Ps[wid][(lane >> 4) * 4 + r][nj * 16 + l16] = f2bf(pv);
            }
        }
        // ---- O += P V ----
        short8 pa[2];
        #pragma unroll
        for (int kk = 0; kk < 2; kk++)
            pa[kk] = *reinterpret_cast<const short8*>(&Ps[wid][l16][kk * 32 + lk]);
        #pragma unroll
        for (int nd = 0; nd < 4; nd++) {
            #pragma unroll
            for (int kk = 0; kk < 2; kk++) {
                short8 vf = *reinterpret_cast<const short8*>(&Vt[cur][nd * 16 + l16][kk * 32 + lk]);
                o_acc[nd] = __builtin_amdgcn_mfma_f32_16x16x32_bf16(pa[kk], vf, o_acc[nd], 0, 0, 0);
            }
        }

        if (t + 1 < 16) {
            *reinterpret_cast<uint4*>(&Ks[nxt][krr][kc8 * 8]) = kreg;
            *reinterpret_cast<ushort2*>(&Vt[nxt][vdq * 4 + 0][vs]) = make_ushort2(vra.x, vrb.x);
            *reinterpret_cast<ushort2*>(&Vt[nxt][vdq * 4 + 1][vs]) = make_ushort2(vra.y, vrb.y);
            *reinterpret_cast<ushort2*>(&Vt[nxt][vdq * 4 + 2][vs]) = make_ushort2(vra.z, vrb.z);
            *reinterpret_cast<ushort2*>(&Vt[nxt][vdq * 4 + 3][vs]) = make_ushort2(vra.w, vrb.w);
        }
        __syncthreads();
    }

    float inv[4];
    #pragma unroll
    for (int r = 0; r < 4; r++) {
        float s = l_part[r];
        #pragma unroll
        for (int off = 8; off >= 1; off >>= 1) s += __shfl_xor(s, off);
        inv[r] = 1.f / s;
    }
    const int rowb = b * 1024 + qt * 128 + wid * 16 + (lane >> 4) * 4;
    #pragma unroll
    for (int nd = 0; nd < 4; nd++) {
        const int col = h * 64 + nd * 16 + l16;
        #pragma unroll
        for (int r = 0; r < 4; r++) {
            y[(size_t)(rowb + r) * 768 + col] = f2bf(o_acc[nd][r] * inv[r]);
        }
    }
}

// ---------------- driver ----------------
extern "C" void kernel_launch(void* const* d_in, const int* in_sizes, int n_in,
                              void* d_out, int out_size, void* d_ws, size_t ws_size,
                              hipStream_t stream) {
    (void)in_sizes; (void)n_in; (void)out_size;
    const int*   idx    = (const int*)d_in[0];
    const float* wte    = (const float*)d_in[1];
    const float* wpe    = (const float*)d_in[2];
    const float* ln1w   = (const float*)d_in[3];
    const float* ln1b   = (const float*)d_in[4];
    const float* attnw  = (const float*)d_in[5];
    const float* attnb  = (const float*)d_in[6];
    const float* projw  = (const float*)d_in[7];
    const float* projb  = (const float*)d_in[8];
    const float* ln2w   = (const float*)d_in[9];
    const float* ln2b   = (const float*)d_in[10];
    const float* fcw    = (const float*)d_in[11];
    const float* fcb    = (const float*)d_in[12];
    const float* mprojw = (const float*)d_in[13];
    const float* mprojb = (const float*)d_in[14];
    const float* lnfw   = (const float*)d_in[15];
    const float* lnfb   = (const float*)d_in[16];
    const float* lmw    = (const float*)d_in[17];
    float* out = (float*)d_out;

    // ---- workspace layout ----
    char* p = (char*)d_ws;
    size_t used = 0;
    auto take = [&](size_t bytes) { char* q = p + used; used += (bytes + 255) & ~(size_t)255; return q; };
    float* x      = (float*)take((size_t)4096 * 768 * 4);
    u16*   a_bf   = (u16*)take((size_t)4096 * 768 * 2);
    u16*   qkv_bf = (u16*)take((size_t)4096 * 2304 * 2);
    u16*   hid_bf = (u16*)take((size_t)4096 * 3072 * 2);
    u16*   w_lm   = (u16*)take((size_t)30592 * 768 * 2);
    const bool castLm = used <= ws_size;
    u16*   w_attn = (u16*)take((size_t)12 * 2304 * 768 * 2);
    u16*   w_proj = (u16*)take((size_t)12 * 768 * 768 * 2);
    u16*   w_fc   = (u16*)take((size_t)12 * 3072 * 768 * 2);
    u16*   w_mprj = (u16*)take((size_t)12 * 768 * 3072 * 2);
    const bool castAll = used <= ws_size;

    embed_kernel<<<4096, 256, 0, stream>>>(idx, wte, wpe, x);

    if (castLm)
        castw_kernel<<<2048, 256, 0, stream>>>(lmw, w_lm, (long)30522 * 768, (long)30592 * 768);
    if (castAll) {
        castw_kernel<<<2048, 256, 0, stream>>>(attnw,  w_attn, (long)12 * 2304 * 768, (long)12 * 2304 * 768);
        castw_kernel<<<2048, 256, 0, stream>>>(projw,  w_proj, (long)12 * 768 * 768,  (long)12 * 768 * 768);
        castw_kernel<<<2048, 256, 0, stream>>>(fcw,    w_fc,   (long)12 * 3072 * 768, (long)12 * 3072 * 768);
        castw_kernel<<<2048, 256, 0, stream>>>(mprojw, w_mprj, (long)12 * 768 * 3072, (long)12 * 768 * 3072);
    }

    for (int l = 0; l < 12; l++) {
        ln_kernel<<<1024, 256, 0, stream>>>(x, ln1w + l * 768, ln1b + l * 768, a_bf);
        if (castAll) {
            gemm_big<0, 0><<<16 * 18, 512, 0, stream>>>(
                a_bf, 768, w_attn + (size_t)l * 2304 * 768, 768, attnb + l * 2304,
                (void*)qkv_bf, 2304, 2304, 768, 16);
        } else {
            gemm_bt<0><<<dim3(18, 32), 256, 0, stream>>>(
                a_bf, 768, attnw + (size_t)l * 2304 * 768, 768, attnb + l * 2304,
                (void*)qkv_bf, 2304, 4096, 2304, 768, nullptr);
        }
        attn_mfma_kernel<<<dim3(8, 12, 4), 512, 0, stream>>>(qkv_bf, a_bf);
        if (castAll) {
            gemm_splitk<<<192 * 2, 256, 0, stream>>>(
                a_bf, 768, w_proj + (size_t)l * 768 * 768, 768, projb + l * 768,
                768, 384, 32, 192, x);
        } else {
            gemm_bt<1><<<dim3(6, 32), 256, 0, stream>>>(
                a_bf, 768, projw + (size_t)l * 768 * 768, 768, projb + l * 768,
                nullptr, 768, 4096, 768, 768, x);
        }
        ln_kernel<<<1024, 256, 0, stream>>>(x, ln2w + l * 768, ln2b + l * 768, a_bf);
        if (castAll) {
            gemm_big<2, 0><<<16 * 24, 512, 0, stream>>>(
                a_bf, 768, w_fc + (size_t)l * 3072 * 768, 768, fcb + l * 3072,
                (void*)hid_bf, 3072, 3072, 768, 16);
            gemm_splitk<<<192 * 4, 256, 0, stream>>>(
                hid_bf, 3072, w_mprj + (size_t)l * 768 * 3072, 3072, mprojb + l * 768,
                768, 768, 32, 192, x);
        } else {
            gemm_bt<2><<<dim3(24, 32), 256, 0, stream>>>(
                a_bf, 768, fcw + (size_t)l * 3072 * 768, 768, fcb + l * 3072,
                (void*)hid_bf, 3072, 4096, 3072, 768, nullptr);
            gemm_bt<1><<<dim3(6, 32), 256, 0, stream>>>(
                hid_bf, 3072, mprojw + (size_t)l * 768 * 3072, 3072, mprojb + l * 768,
                nullptr, 768, 4096, 768, 3072, x);
        }
    }

    ln_kernel<<<1024, 256, 0, stream>>>(x, lnfw, lnfb, a_bf);
    if (castLm) {
        gemm_big<3, 1><<<16 * 239, 512, 0, stream>>>(
            a_bf, 768, w_lm, 768, nullptr, (void*)out, 30522, 30522, 768, 239);
    } else {
        gemm_bt<3><<<dim3(239, 32), 256, 0, stream>>>(
            a_bf, 768, lmw, 768, nullptr, (void*)out, 30522, 4096, 30522, 768, nullptr);
    }
}

// Round 11
// 2722.776 us; speedup vs baseline: 1.1161x; 1.1003x over previous
//
#include <hip/hip_runtime.h>
#include <hip/hip_bf16.h>
#include <math.h>

// ---------------- types & helpers ----------------
typedef __attribute__((ext_vector_type(8))) short short8;   // 8 x bf16 (4 VGPRs)
typedef __attribute__((ext_vector_type(4))) float f32x4;

typedef unsigned short u16;

__device__ __forceinline__ u16 f2bf(float f) {
    union { float f; unsigned int u; } v; v.f = f;
    unsigned int u = v.u;
    unsigned int r = (u + 0x7fffu + ((u >> 16) & 1u)) >> 16;  // RNE
    return (u16)r;
}
__device__ __forceinline__ float bf2f(u16 u) {
    union { unsigned int u; float f; } v; v.u = ((unsigned int)u) << 16;
    return v.f;
}

// async global->LDS 16B copy (wave base + lane*16 dest, per-lane global src).
__device__ __forceinline__ void gload16(const void* g, void* l) {
    __builtin_amdgcn_global_load_lds(
        (const __attribute__((address_space(1))) void*)g,
        (__attribute__((address_space(3))) void*)l, 16, 0, 0);
}

// ---------------- weight cast: f32 -> bf16 (pad region zeroed) ----------------
__global__ __launch_bounds__(256) void castw_kernel(const float* __restrict__ src,
                                                    u16* __restrict__ dst,
                                                    long n, long npad) {
    long i = ((long)blockIdx.x * 256 + threadIdx.x) * 4;
    const long stride = (long)gridDim.x * 1024;
    for (; i < npad; i += stride) {
        ushort4 o;
        if (i < n) {
            float4 v = *reinterpret_cast<const float4*>(src + i);
            o.x = f2bf(v.x); o.y = f2bf(v.y); o.z = f2bf(v.z); o.w = f2bf(v.w);
        } else {
            o = make_ushort4(0, 0, 0, 0);
        }
        *reinterpret_cast<ushort4*>(dst + i) = o;
    }
}

// ---------------- embed: x = wte[idx] + wpe[t] ----------------
__global__ __launch_bounds__(256) void embed_kernel(const int* __restrict__ idx,
                                                    const float* __restrict__ wte,
                                                    const float* __restrict__ wpe,
                                                    float* __restrict__ x) {
    const int row = blockIdx.x;            // b*1024 + t
    const int tid = threadIdx.x;
    const int t = row & 1023;
    const int tok = idx[row];
    const float* we = wte + (size_t)tok * 768;
    const float* pe = wpe + (size_t)t * 768;
    float* xr = x + (size_t)row * 768;
    xr[tid]       = we[tid]       + pe[tid];
    xr[tid + 256] = we[tid + 256] + pe[tid + 256];
    xr[tid + 512] = we[tid + 512] + pe[tid + 512];
}

// ---------------- LayerNorm: wave-per-row (no LDS, no barriers) ----------------
__global__ __launch_bounds__(256) void ln_kernel(const float* __restrict__ x,
                                                 const float* __restrict__ w,
                                                 const float* __restrict__ b,
                                                 u16* __restrict__ out) {
    const int wid = threadIdx.x >> 6, lane = threadIdx.x & 63;
    const int row = blockIdx.x * 4 + wid;
    const float* xr = x + (size_t)row * 768;
    const float4 v0 = *reinterpret_cast<const float4*>(xr + lane * 4);
    const float4 v1 = *reinterpret_cast<const float4*>(xr + 256 + lane * 4);
    const float4 v2 = *reinterpret_cast<const float4*>(xr + 512 + lane * 4);
    float s = v0.x + v0.y + v0.z + v0.w + v1.x + v1.y + v1.z + v1.w
            + v2.x + v2.y + v2.z + v2.w;
    float q = v0.x * v0.x + v0.y * v0.y + v0.z * v0.z + v0.w * v0.w
            + v1.x * v1.x + v1.y * v1.y + v1.z * v1.z + v1.w * v1.w
            + v2.x * v2.x + v2.y * v2.y + v2.z * v2.z + v2.w * v2.w;
    #pragma unroll
    for (int off = 32; off >= 1; off >>= 1) {
        s += __shfl_xor(s, off);
        q += __shfl_xor(q, off);
    }
    const float mean = s * (1.f / 768.f);
    const float var = q * (1.f / 768.f) - mean * mean;
    const float rstd = rsqrtf(var + 1e-5f);
    u16* orow = out + (size_t)row * 768;
    #pragma unroll
    for (int seg = 0; seg < 3; seg++) {
        const float4 v = seg == 0 ? v0 : (seg == 1 ? v1 : v2);
        const float4 wv = *reinterpret_cast<const float4*>(w + seg * 256 + lane * 4);
        const float4 bv = *reinterpret_cast<const float4*>(b + seg * 256 + lane * 4);
        ushort4 ov;
        ov.x = f2bf((v.x - mean) * rstd * wv.x + bv.x);
        ov.y = f2bf((v.y - mean) * rstd * wv.y + bv.y);
        ov.z = f2bf((v.z - mean) * rstd * wv.z + bv.z);
        ov.w = f2bf((v.w - mean) * rstd * wv.w + bv.w);
        *reinterpret_cast<ushort4*>(orow + seg * 256 + lane * 4) = ov;
    }
}

// =========== 256x128-tile 2-phase GEMM, 512 threads ==================
// C[m,n] = sum_k A[m,k]*B[n,k].  BM=256, BN=128, BK=32.  8 waves = 4M x 2N.
// 2-phase dbuf, counted vmcnt(3).  LDS quarter-swizzle q' = q ^ ((row>>1)&3)
// (verified: bank conflicts -> 0).  ORDER: 0 = m-fastest, 1 = n-fastest.
// SWZ: 1 = bijective XCD swizzle (B-panel reuse within XCD); 0 = plain launch
// order (for lm_head: all XCDs sweep the same n-window together so A and the
// active B panels stay L3-resident despite the C-write stream).
// EPI: 0 = +bias -> bf16; 2 = +bias+GELU -> bf16; 3 = plain f32 (n<N guard,
//      stride-76 LDS transpose + float4 stores)
template<int EPI, int ORDER, int SWZ>
__global__ __launch_bounds__(512) void gemm_big(
        const u16* __restrict__ A, int lda,
        const u16* __restrict__ B, int ldb,
        const float* __restrict__ bias,
        void* __restrict__ Cout, int ldc,
        int N, int K, int nmt) {
    __shared__ __align__(16) u16 lds[2][384 * 32];   // [buf]: A = [0,8192) u16, B = [8192,12288)
    const int tid = threadIdx.x;
    const int lane = tid & 63, wid = tid >> 6;
    const int nwg = gridDim.x;
    const int o = blockIdx.x;
    const int wg = SWZ ? ((o & 7) * (nwg >> 3) + (o >> 3)) : o;
    int m0, n0;
    if (ORDER == 0) { m0 = (wg % nmt) * 256; n0 = (wg / nmt) * 128; }
    else            { n0 = (wg % nmt) * 128; m0 = (wg / nmt) * 256; }

    const int wm = (wid >> 1) * 64, wn = (wid & 1) * 64;
    const int l16 = lane & 15;
    const int qid = lane >> 4;
    const int xq8 = ((qid ^ ((l16 >> 1) & 3)) * 8);   // swizzled read quarter

    const int ar = tid >> 2, aq = (tid & 3) ^ ((ar >> 1) & 3);
    const size_t a_src0 = (size_t)(m0 + ar) * lda + aq * 8;
    const size_t a_src1 = (size_t)(m0 + ar + 128) * lda + aq * 8;
    const size_t b_src = (size_t)(n0 + ar) * ldb + aq * 8;

    f32x4 acc[4][4];
    #pragma unroll
    for (int i = 0; i < 4; i++)
        #pragma unroll
        for (int j = 0; j < 4; j++)
            acc[i][j] = (f32x4){0.f, 0.f, 0.f, 0.f};

    const int nk = K >> 5;
    gload16(A + a_src0, lds[0] + tid * 8);
    gload16(A + a_src1, lds[0] + tid * 8 + 4096);
    gload16(B + b_src,  lds[0] + tid * 8 + 8192);

    for (int t = 0; t < nk; ++t) {
        if (t + 1 < nk) {
            u16* buf = lds[(t + 1) & 1];
            const int k0 = (t + 1) << 5;
            gload16(A + a_src0 + k0, buf + tid * 8);
            gload16(A + a_src1 + k0, buf + tid * 8 + 4096);
            gload16(B + b_src + k0,  buf + tid * 8 + 8192);
            asm volatile("s_waitcnt vmcnt(3)" ::: "memory");
        } else {
            asm volatile("s_waitcnt vmcnt(0)" ::: "memory");
        }
        __builtin_amdgcn_s_barrier();
        asm volatile("" ::: "memory");
        const u16* As = lds[t & 1];
        const u16* Bs = lds[t & 1] + 8192;
        short8 af[4], bf[4];
        #pragma unroll
        for (int i = 0; i < 4; i++) {
            af[i] = *reinterpret_cast<const short8*>(&As[(wm + i * 16 + l16) * 32 + xq8]);
            bf[i] = *reinterpret_cast<const short8*>(&Bs[(wn + i * 16 + l16) * 32 + xq8]);
        }
        #pragma unroll
        for (int mi = 0; mi < 4; mi++)
            #pragma unroll
            for (int ni = 0; ni < 4; ni++)
                acc[mi][ni] = __builtin_amdgcn_mfma_f32_16x16x32_bf16(af[mi], bf[ni], acc[mi][ni], 0, 0, 0);
        asm volatile("" ::: "memory");
        __builtin_amdgcn_s_barrier();
    }

    if (EPI == 3) {
        float* ct = reinterpret_cast<float*>(&lds[0][0]) + wid * 1216;  // 16 x 76 f32
        const int rw = (lane >> 4) * 4;
        const int rr = lane >> 2;
        const int rc = (lane & 3) * 16;
        #pragma unroll
        for (int mi = 0; mi < 4; mi++) {
            asm volatile("" ::: "memory");
            #pragma unroll
            for (int ni = 0; ni < 4; ni++)
                #pragma unroll
                for (int j = 0; j < 4; j++)
                    ct[(rw + j) * 76 + ni * 16 + l16] = acc[mi][ni][j];
            asm volatile("" ::: "memory");
            const int m = m0 + wm + mi * 16 + rr;
            const int nb = n0 + wn + rc;
            float* crow = (float*)Cout + (size_t)m * ldc + nb;
            #pragma unroll
            for (int q = 0; q < 4; q++) {
                const f32x4 v = *reinterpret_cast<const f32x4*>(&ct[rr * 76 + rc + q * 4]);
                if (nb + q * 4 + 3 < N) {
                    *reinterpret_cast<f32x4*>(crow + q * 4) = v;
                } else {
                    #pragma unroll
                    for (int e = 0; e < 4; e++)
                        if (nb + q * 4 + e < N) crow[q * 4 + e] = v[e];
                }
            }
            asm volatile("" ::: "memory");
            __builtin_amdgcn_s_barrier();
        }
    } else {
        const int cb = n0 + wn + l16;
        const int rb = m0 + wm + (lane >> 4) * 4;
        #pragma unroll
        for (int ni = 0; ni < 4; ni++) {
            const int n = cb + ni * 16;
            const float bv = bias[n];
            #pragma unroll
            for (int mi = 0; mi < 4; mi++) {
                #pragma unroll
                for (int j = 0; j < 4; j++) {
                    const int m = rb + mi * 16 + j;
                    float v = acc[mi][ni][j] + bv;
                    if (EPI == 0) {
                        ((u16*)Cout)[(size_t)m * ldc + n] = f2bf(v);
                    } else {
                        const float t = tanhf(0.7978845608028654f * (v + 0.044715f * v * v * v));
                        ((u16*)Cout)[(size_t)m * ldc + n] = f2bf(0.5f * v * (1.f + t));
                    }
                }
            }
        }
    }
}

// ============ 128x64-tile 2-phase GEMM: resid += A*B^T + bias (no atomics) =========
// 256 threads = 4 waves (2M x 2N, each 64x32).  Same proven 2-phase vmcnt(3) loop.
// 384 blocks for proj/mproj (1.5 blocks/CU) -- replaces atomic split-K.
__global__ __launch_bounds__(256) void gemm_half(
        const u16* __restrict__ A, int lda,
        const u16* __restrict__ B, int ldb,
        const float* __restrict__ bias,
        int ldc, int K, int nmt,
        float* __restrict__ resid) {
    __shared__ __align__(16) u16 lds[2][192 * 32];   // [buf]: A = [0,4096) u16, B = [4096,6144)
    const int tid = threadIdx.x;
    const int lane = tid & 63, wid = tid >> 6;
    const int nwg = gridDim.x;
    const int o = blockIdx.x;
    const int wg = (o & 7) * (nwg >> 3) + (o >> 3);   // XCD swizzle (grid%8==0)
    const int m0 = (wg % nmt) * 128, n0 = (wg / nmt) * 64;

    const int wm = (wid >> 1) * 64, wn = (wid & 1) * 32;
    const int l16 = lane & 15;
    const int qid = lane >> 4;
    const int xq8 = ((qid ^ ((l16 >> 1) & 3)) * 8);

    // staging: A = 512 chunks (2/thread), B = 256 chunks (1/thread)
    const int ar = tid >> 2, aq = (tid & 3) ^ ((ar >> 1) & 3);
    const size_t a_src0 = (size_t)(m0 + ar) * lda + aq * 8;
    const size_t a_src1 = (size_t)(m0 + ar + 64) * lda + aq * 8;
    const size_t b_src = (size_t)(n0 + (tid >> 2)) * ldb + aq * 8;  // rows 0..63

    f32x4 acc[4][2];
    #pragma unroll
    for (int i = 0; i < 4; i++)
        #pragma unroll
        for (int j = 0; j < 2; j++)
            acc[i][j] = (f32x4){0.f, 0.f, 0.f, 0.f};

    const int nk = K >> 5;
    gload16(A + a_src0, lds[0] + tid * 8);
    gload16(A + a_src1, lds[0] + tid * 8 + 2048);
    gload16(B + b_src,  lds[0] + tid * 8 + 4096);

    for (int t = 0; t < nk; ++t) {
        if (t + 1 < nk) {
            u16* buf = lds[(t + 1) & 1];
            const int k0 = (t + 1) << 5;
            gload16(A + a_src0 + k0, buf + tid * 8);
            gload16(A + a_src1 + k0, buf + tid * 8 + 2048);
            gload16(B + b_src + k0,  buf + tid * 8 + 4096);
            asm volatile("s_waitcnt vmcnt(3)" ::: "memory");
        } else {
            asm volatile("s_waitcnt vmcnt(0)" ::: "memory");
        }
        __builtin_amdgcn_s_barrier();
        asm volatile("" ::: "memory");
        const u16* As = lds[t & 1];
        const u16* Bs = lds[t & 1] + 4096;
        short8 af[4], bf[2];
        #pragma unroll
        for (int i = 0; i < 4; i++)
            af[i] = *reinterpret_cast<const short8*>(&As[(wm + i * 16 + l16) * 32 + xq8]);
        #pragma unroll
        for (int j = 0; j < 2; j++)
            bf[j] = *reinterpret_cast<const short8*>(&Bs[(wn + j * 16 + l16) * 32 + xq8]);
        #pragma unroll
        for (int mi = 0; mi < 4; mi++)
            #pragma unroll
            for (int ni = 0; ni < 2; ni++)
                acc[mi][ni] = __builtin_amdgcn_mfma_f32_16x16x32_bf16(af[mi], bf[ni], acc[mi][ni], 0, 0, 0);
        asm volatile("" ::: "memory");
        __builtin_amdgcn_s_barrier();
    }

    const int cb = n0 + wn + l16;
    const int rb = m0 + wm + (lane >> 4) * 4;
    #pragma unroll
    for (int ni = 0; ni < 2; ni++) {
        const int n = cb + ni * 16;
        const float bv = bias[n];
        #pragma unroll
        for (int mi = 0; mi < 4; mi++) {
            #pragma unroll
            for (int j = 0; j < 4; j++) {
                const int m = rb + mi * 16 + j;
                resid[(size_t)m * ldc + n] += acc[mi][ni][j] + bv;
            }
        }
    }
}

// ---------------- fallback GEMM (B fp32, reg-staged) -- used only if ws too small ---
template<int EPI>
__global__ __launch_bounds__(256, 2) void gemm_bt(
        const u16* __restrict__ A, int lda,
        const float* __restrict__ B, int ldb,
        const float* __restrict__ bias,
        void* __restrict__ Cout, int ldc,
        int M, int N, int K,
        float* __restrict__ resid) {
    __shared__ __align__(16) u16 As[128][40];
    __shared__ __align__(16) u16 Bs[128][40];
    const int tid = threadIdx.x;
    const int lane = tid & 63, wid = tid >> 6;
    const int m0 = blockIdx.y * 128, n0 = blockIdx.x * 128;
    const int wm = (wid >> 1) * 64, wn = (wid & 1) * 64;
    const int l16 = lane & 15, lk = (lane >> 4) * 8;

    f32x4 acc[4][4];
    #pragma unroll
    for (int i = 0; i < 4; i++)
        #pragma unroll
        for (int j = 0; j < 4; j++)
            acc[i][j] = (f32x4){0.f, 0.f, 0.f, 0.f};

    for (int k0 = 0; k0 < K; k0 += 32) {
        #pragma unroll
        for (int p = 0; p < 2; p++) {
            const int e = p * 256 + tid;
            const int r = e >> 2, c = e & 3;
            uint4 v = *reinterpret_cast<const uint4*>(A + (size_t)(m0 + r) * lda + k0 + c * 8);
            *reinterpret_cast<uint4*>(&As[r][c * 8]) = v;
        }
        #pragma unroll
        for (int p = 0; p < 4; p++) {
            const int e = p * 256 + tid;
            const int r = e >> 3, c = e & 7;
            float4 v = make_float4(0.f, 0.f, 0.f, 0.f);
            if (n0 + r < N)
                v = *reinterpret_cast<const float4*>(B + (size_t)(n0 + r) * ldb + k0 + c * 4);
            ushort4 hv;
            hv.x = f2bf(v.x); hv.y = f2bf(v.y); hv.z = f2bf(v.z); hv.w = f2bf(v.w);
            *reinterpret_cast<ushort4*>(&Bs[r][c * 4]) = hv;
        }
        __syncthreads();
        short8 af[4], bfr[4];
        #pragma unroll
        for (int i = 0; i < 4; i++) {
            af[i]  = *reinterpret_cast<const short8*>(&As[wm + i * 16 + l16][lk]);
            bfr[i] = *reinterpret_cast<const short8*>(&Bs[wn + i * 16 + l16][lk]);
        }
        #pragma unroll
        for (int mi = 0; mi < 4; mi++)
            #pragma unroll
            for (int ni = 0; ni < 4; ni++)
                acc[mi][ni] = __builtin_amdgcn_mfma_f32_16x16x32_bf16(af[mi], bfr[ni], acc[mi][ni], 0, 0, 0);
        __syncthreads();
    }

    const int cb = n0 + wn + l16;
    const int rb = m0 + wm + (lane >> 4) * 4;
    #pragma unroll
    for (int ni = 0; ni < 4; ni++) {
        const int n = cb + ni * 16;
        if (n >= N) continue;
        float bv = 0.f;
        if (EPI != 3) bv = bias[n];
        #pragma unroll
        for (int mi = 0; mi < 4; mi++) {
            #pragma unroll
            for (int j = 0; j < 4; j++) {
                const int m = rb + mi * 16 + j;
                float v = acc[mi][ni][j] + bv;
                if (EPI == 0) {
                    ((u16*)Cout)[(size_t)m * ldc + n] = f2bf(v);
                } else if (EPI == 1) {
                    resid[(size_t)m * ldc + n] += v;
                } else if (EPI == 2) {
                    const float t = tanhf(0.7978845608028654f * (v + 0.044715f * v * v * v));
                    ((u16*)Cout)[(size_t)m * ldc + n] = f2bf(0.5f * v * (1.f + t));
                } else {
                    ((float*)Cout)[(size_t)m * ldc + n] = v;
                }
            }
        }
    }
}

// ---------------- MFMA flash attention: QBLK=128, 512 threads, K/V dbuf -----------
// 8 waves; wave w owns q-rows w*16..w*16+15.  One barrier per KV-tile; global
// loads for tile t+1 issue (regs) before compute(t), LDS-write after (T14).
__global__ __launch_bounds__(512, 2) void attn_mfma_kernel(const u16* __restrict__ qkv,
                                                           u16* __restrict__ y) {
    __shared__ __align__(16) u16 Qs[128][72];
    __shared__ __align__(16) u16 Ks[2][64][72];
    __shared__ __align__(16) u16 Vt[2][64][72];  // transposed: Vt[.][d][s]
    __shared__ __align__(16) u16 Ps[8][16][72];  // per-wave P tile (bf16)

    const int tid = threadIdx.x;
    const int lane = tid & 63, wid = tid >> 6;
    const int l16 = lane & 15, lk = (lane >> 4) * 8;
    const int qt = blockIdx.x, h = blockIdx.y, b = blockIdx.z;

    const size_t base = (size_t)b * 1024 * 2304;
    const u16* qp = qkv + base + (size_t)(qt * 128) * 2304 + h * 64;
    const u16* kp = qkv + base + 768  + h * 64;
    const u16* vp = qkv + base + 1536 + h * 64;

    // staging coords (per thread, fixed): one K chunk + one V row-pair each
    const int krr = tid >> 3, kc8 = tid & 7;       // K: 64 rows x 8 chunks = 512
    const int vs = (tid >> 4) * 2, vdq = tid & 15; // V: 32 row-pairs x 16 dq = 512

    // ---- stage Q (128 x 64); load tile-0 K/V to regs ----
    #pragma unroll
    for (int p = 0; p < 2; p++) {
        const int e = p * 512 + tid;
        const int rr = e >> 3, c8 = e & 7;
        *reinterpret_cast<uint4*>(&Qs[rr][c8 * 8]) =
            *reinterpret_cast<const uint4*>(qp + (size_t)rr * 2304 + c8 * 8);
    }
    uint4 kreg; ushort4 vra, vrb;
    kreg = *reinterpret_cast<const uint4*>(kp + (size_t)krr * 2304 + kc8 * 8);
    vra = *reinterpret_cast<const ushort4*>(vp + (size_t)vs * 2304 + vdq * 4);
    vrb = *reinterpret_cast<const ushort4*>(vp + (size_t)(vs + 1) * 2304 + vdq * 4);
    __syncthreads();   // Qs ready

    short8 qf[2];
    #pragma unroll
    for (int kk = 0; kk < 2; kk++)
        qf[kk] = *reinterpret_cast<const short8*>(&Qs[wid * 16 + l16][kk * 32 + lk]);

    // write tile 0 into buf 0
    *reinterpret_cast<uint4*>(&Ks[0][krr][kc8 * 8]) = kreg;
    *reinterpret_cast<ushort2*>(&Vt[0][vdq * 4 + 0][vs]) = make_ushort2(vra.x, vrb.x);
    *reinterpret_cast<ushort2*>(&Vt[0][vdq * 4 + 1][vs]) = make_ushort2(vra.y, vrb.y);
    *reinterpret_cast<ushort2*>(&Vt[0][vdq * 4 + 2][vs]) = make_ushort2(vra.z, vrb.z);
    *reinterpret_cast<ushort2*>(&Vt[0][vdq * 4 + 3][vs]) = make_ushort2(vra.w, vrb.w);
    __syncthreads();   // tile 0 in LDS

    f32x4 o_acc[4];
    #pragma unroll
    for (int i = 0; i < 4; i++) o_acc[i] = (f32x4){0.f, 0.f, 0.f, 0.f};
    float l_part[4] = {0.f, 0.f, 0.f, 0.f};

    for (int t = 0; t < 16; ++t) {
        const int cur = t & 1, nxt = cur ^ 1;
        if (t + 1 < 16) {
            const int s0 = (t + 1) * 64;
            kreg = *reinterpret_cast<const uint4*>(kp + (size_t)(s0 + krr) * 2304 + kc8 * 8);
            vra = *reinterpret_cast<const ushort4*>(vp + (size_t)(s0 + vs) * 2304 + vdq * 4);
            vrb = *reinterpret_cast<const ushort4*>(vp + (size_t)(s0 + vs + 1) * 2304 + vdq * 4);
        }

        // ---- S = Q K^T (16 x 64 per wave) ----
        f32x4 sa[4];
        #pragma unroll
        for (int i = 0; i < 4; i++) sa[i] = (f32x4){0.f, 0.f, 0.f, 0.f};
        #pragma unroll
        for (int nj = 0; nj < 4; nj++) {
            #pragma unroll
            for (int kk = 0; kk < 2; kk++) {
                short8 kf = *reinterpret_cast<const short8*>(&Ks[cur][nj * 16 + l16][kk * 32 + lk]);
                sa[nj] = __builtin_amdgcn_mfma_f32_16x16x32_bf16(qf[kk], kf, sa[nj], 0, 0, 0);
            }
        }
        // ---- P = exp(S*scale), row sums, Ps(bf16) ----
        #pragma unroll
        for (int nj = 0; nj < 4; nj++) {
            #pragma unroll
            for (int r = 0; r < 4; r++) {
                const float pv = __expf(sa[nj][r] * 0.125f);
                l_part[r] += pv;
                Ps[wid][(lane >> 4) * 4 + r][nj * 16 + l16] = f2bf(pv);
            }
        }
        // ---- O += P V ----
        short8 pa[2];
        #pragma unroll
        for (int kk = 0; kk < 2; kk++)
            pa[kk] = *reinterpret_cast<const short8*>(&Ps[wid][l16][kk * 32 + lk]);
        #pragma unroll
        for (int nd = 0; nd < 4; nd++) {
            #pragma unroll
            for (int kk = 0; kk < 2; kk++) {
                short8 vf = *reinterpret_cast<const short8*>(&Vt[cur][nd * 16 + l16][kk * 32 + lk]);
                o_acc[nd] = __builtin_amdgcn_mfma_f32_16x16x32_bf16(pa[kk], vf, o_acc[nd], 0, 0, 0);
            }
        }

        if (t + 1 < 16) {
            *reinterpret_cast<uint4*>(&Ks[nxt][krr][kc8 * 8]) = kreg;
            *reinterpret_cast<ushort2*>(&Vt[nxt][vdq * 4 + 0][vs]) = make_ushort2(vra.x, vrb.x);
            *reinterpret_cast<ushort2*>(&Vt[nxt][vdq * 4 + 1][vs]) = make_ushort2(vra.y, vrb.y);
            *reinterpret_cast<ushort2*>(&Vt[nxt][vdq * 4 + 2][vs]) = make_ushort2(vra.z, vrb.z);
            *reinterpret_cast<ushort2*>(&Vt[nxt][vdq * 4 + 3][vs]) = make_ushort2(vra.w, vrb.w);
        }
        __syncthreads();
    }

    float inv[4];
    #pragma unroll
    for (int r = 0; r < 4; r++) {
        float s = l_part[r];
        #pragma unroll
        for (int off = 8; off >= 1; off >>= 1) s += __shfl_xor(s, off);
        inv[r] = 1.f / s;
    }
    const int rowb = b * 1024 + qt * 128 + wid * 16 + (lane >> 4) * 4;
    #pragma unroll
    for (int nd = 0; nd < 4; nd++) {
        const int col = h * 64 + nd * 16 + l16;
        #pragma unroll
        for (int r = 0; r < 4; r++) {
            y[(size_t)(rowb + r) * 768 + col] = f2bf(o_acc[nd][r] * inv[r]);
        }
    }
}

// ---------------- driver ----------------
extern "C" void kernel_launch(void* const* d_in, const int* in_sizes, int n_in,
                              void* d_out, int out_size, void* d_ws, size_t ws_size,
                              hipStream_t stream) {
    (void)in_sizes; (void)n_in; (void)out_size;
    const int*   idx    = (const int*)d_in[0];
    const float* wte    = (const float*)d_in[1];
    const float* wpe    = (const float*)d_in[2];
    const float* ln1w   = (const float*)d_in[3];
    const float* ln1b   = (const float*)d_in[4];
    const float* attnw  = (const float*)d_in[5];
    const float* attnb  = (const float*)d_in[6];
    const float* projw  = (const float*)d_in[7];
    const float* projb  = (const float*)d_in[8];
    const float* ln2w   = (const float*)d_in[9];
    const float* ln2b   = (const float*)d_in[10];
    const float* fcw    = (const float*)d_in[11];
    const float* fcb    = (const float*)d_in[12];
    const float* mprojw = (const float*)d_in[13];
    const float* mprojb = (const float*)d_in[14];
    const float* lnfw   = (const float*)d_in[15];
    const float* lnfb   = (const float*)d_in[16];
    const float* lmw    = (const float*)d_in[17];
    float* out = (float*)d_out;

    // ---- workspace layout ----
    char* p = (char*)d_ws;
    size_t used = 0;
    auto take = [&](size_t bytes) { char* q = p + used; used += (bytes + 255) & ~(size_t)255; return q; };
    float* x      = (float*)take((size_t)4096 * 768 * 4);
    u16*   a_bf   = (u16*)take((size_t)4096 * 768 * 2);
    u16*   qkv_bf = (u16*)take((size_t)4096 * 2304 * 2);
    u16*   hid_bf = (u16*)take((size_t)4096 * 3072 * 2);
    u16*   w_lm   = (u16*)take((size_t)30592 * 768 * 2);
    const bool castLm = used <= ws_size;
    u16*   w_attn = (u16*)take((size_t)12 * 2304 * 768 * 2);
    u16*   w_proj = (u16*)take((size_t)12 * 768 * 768 * 2);
    u16*   w_fc   = (u16*)take((size_t)12 * 3072 * 768 * 2);
    u16*   w_mprj = (u16*)take((size_t)12 * 768 * 3072 * 2);
    const bool castAll = used <= ws_size;

    embed_kernel<<<4096, 256, 0, stream>>>(idx, wte, wpe, x);

    if (castLm)
        castw_kernel<<<2048, 256, 0, stream>>>(lmw, w_lm, (long)30522 * 768, (long)30592 * 768);
    if (castAll) {
        castw_kernel<<<2048, 256, 0, stream>>>(attnw,  w_attn, (long)12 * 2304 * 768, (long)12 * 2304 * 768);
        castw_kernel<<<2048, 256, 0, stream>>>(projw,  w_proj, (long)12 * 768 * 768,  (long)12 * 768 * 768);
        castw_kernel<<<2048, 256, 0, stream>>>(fcw,    w_fc,   (long)12 * 3072 * 768, (long)12 * 3072 * 768);
        castw_kernel<<<2048, 256, 0, stream>>>(mprojw, w_mprj, (long)12 * 768 * 3072, (long)12 * 768 * 3072);
    }

    for (int l = 0; l < 12; l++) {
        ln_kernel<<<1024, 256, 0, stream>>>(x, ln1w + l * 768, ln1b + l * 768, a_bf);
        if (castAll) {
            gemm_big<0, 0, 1><<<16 * 18, 512, 0, stream>>>(
                a_bf, 768, w_attn + (size_t)l * 2304 * 768, 768, attnb + l * 2304,
                (void*)qkv_bf, 2304, 2304, 768, 16);
        } else {
            gemm_bt<0><<<dim3(18, 32), 256, 0, stream>>>(
                a_bf, 768, attnw + (size_t)l * 2304 * 768, 768, attnb + l * 2304,
                (void*)qkv_bf, 2304, 4096, 2304, 768, nullptr);
        }
        attn_mfma_kernel<<<dim3(8, 12, 4), 512, 0, stream>>>(qkv_bf, a_bf);
        if (castAll) {
            gemm_half<<<32 * 12, 256, 0, stream>>>(
                a_bf, 768, w_proj + (size_t)l * 768 * 768, 768, projb + l * 768,
                768, 768, 32, x);
        } else {
            gemm_bt<1><<<dim3(6, 32), 256, 0, stream>>>(
                a_bf, 768, projw + (size_t)l * 768 * 768, 768, projb + l * 768,
                nullptr, 768, 4096, 768, 768, x);
        }
        ln_kernel<<<1024, 256, 0, stream>>>(x, ln2w + l * 768, ln2b + l * 768, a_bf);
        if (castAll) {
            gemm_big<2, 0, 1><<<16 * 24, 512, 0, stream>>>(
                a_bf, 768, w_fc + (size_t)l * 3072 * 768, 768, fcb + l * 3072,
                (void*)hid_bf, 3072, 3072, 768, 16);
            gemm_half<<<32 * 12, 256, 0, stream>>>(
                hid_bf, 3072, w_mprj + (size_t)l * 768 * 3072, 3072, mprojb + l * 768,
                768, 3072, 32, x);
        } else {
            gemm_bt<2><<<dim3(24, 32), 256, 0, stream>>>(
                a_bf, 768, fcw + (size_t)l * 3072 * 768, 768, fcb + l * 3072,
                (void*)hid_bf, 3072, 4096, 3072, 768, nullptr);
            gemm_bt<1><<<dim3(6, 32), 256, 0, stream>>>(
                hid_bf, 3072, mprojw + (size_t)l * 768 * 3072, 3072, mprojb + l * 768,
                nullptr, 768, 4096, 768, 3072, x);
        }
    }

    ln_kernel<<<1024, 256, 0, stream>>>(x, lnfw, lnfb, a_bf);
    if (castLm) {
        gemm_big<3, 0, 0><<<16 * 239, 512, 0, stream>>>(
            a_bf, 768, w_lm, 768, nullptr, (void*)out, 30522, 30522, 768, 16);
    } else {
        gemm_bt<3><<<dim3(239, 32), 256, 0, stream>>>(
            a_bf, 768, lmw, 768, nullptr, (void*)out, 30522, 4096, 30522, 768, nullptr);
    }
}